// Round 9
// baseline (580.167 us; speedup 1.0000x reference)
//
#include <hip/hip_runtime.h>
#include <hip/hip_fp16.h>
#include <math.h>

// Problem constants
#define BB 2
#define SS 400
#define II 80
#define HH 128
#define FF 256          // 2*H
#define NN 401          // S+1
#define G4 512          // 4*H
#define MAXSEG 50
#define NCLS 50
#define KH 100          // rows of W1 / Wc1 / Wb1
#define KP 112          // KH padded to 7*16 for MFMA
#define FRAGF 14336     // floats per frag-packed W (28672 shorts)

// d_out layout (floats): scores | cls | bin | pred | prev
#define SCORES_OFF 0
#define CLS_OFF    (BB*NN*NN)
#define BIN_OFF    (CLS_OFF + BB*SS*NCLS)
#define PRED_OFF   (BIN_OFF + BB*SS*2)
#define PREV_OFF   (PRED_OFF + BB)

// workspace layout (float slots)
#define WS_GX      0                          // 819200; dead after rec -> dpcol (51328)
#define WS_RNN     (WS_GX + 4*SS*G4)          // B*S*F
#define WS_CUM     (WS_RNN + BB*SS*FF)        // B*N*F
#define WS_PXD     (WS_CUM + BB*NN*FF)        // B*N*KP
#define WS_PXE     (WS_PXD + BB*NN*KP)
#define WS_PART    (WS_PXE + BB*NN*KP)        // B*16*F (unused since cum fusion)
#define WS_W2P     (WS_PART + BB*16*FF)       // KP
#define WS_B1P     (WS_W2P + KP)              // KP
#define WS_WHP     (WS_B1P + KP)              // Wh f16 MFMA frags: 131072 halfs
#define WS_WFRAGC  (WS_WHP + 65536)
#define WS_WFRAGD  (WS_WFRAGC + FRAGF)
#define WS_WFRAGE  (WS_WFRAGD + FRAGF)
#define WS_WFRAGHC (WS_WFRAGE + FRAGF)
#define WS_WFRAGHB (WS_WFRAGHC + FRAGF)
#define WS_BC1P    (WS_WFRAGHB + FRAGF)       // KP
#define WS_BB1P    (WS_BC1P + KP)             // KP

typedef __attribute__((ext_vector_type(8))) short short8;
typedef __attribute__((ext_vector_type(4))) float f32x4;
typedef _Float16 f16x2 __attribute__((ext_vector_type(2)));
typedef _Float16 f16x8 __attribute__((ext_vector_type(8)));

__device__ __forceinline__ float prelu_f(float x, float a) {
    return x >= 0.f ? x : a * x;
}
__device__ __forceinline__ unsigned short f2bf(float x) {
    union { float f; unsigned u; } v; v.f = x;
    unsigned r = v.u + 0x7fffu + ((v.u >> 16) & 1u);   // RNE
    return (unsigned short)(r >> 16);
}
__device__ __forceinline__ float fast_sigmoid(float x) {
    return 1.f / (1.f + __expf(-x));
}
__device__ __forceinline__ float fast_tanh(float x) {
    return 1.f - 2.f / (1.f + __expf(2.f * x));
}
__device__ __forceinline__ void barrier_lds() {
    asm volatile("s_waitcnt lgkmcnt(0)\ns_barrier" ::: "memory");
}
// m201-style barrier: LDS drained, but vmcnt (global loads/stores) stays
// in flight across the barrier — no "memory" clobber, no vmcnt drain.
__device__ __forceinline__ void rec_barrier() {
    __builtin_amdgcn_sched_barrier(0);
    asm volatile("s_waitcnt lgkmcnt(0)");
    __builtin_amdgcn_s_barrier();
    __builtin_amdgcn_sched_barrier(0);
}
__device__ __forceinline__ int fragidx(int k, int f) {
    int kt = k >> 4, l15 = k & 15;
    int ks = f >> 5, quad = (f >> 3) & 3, e = f & 7;
    return ((((kt * 8 + ks) * 4 + quad) * 16) + l15) * 8 + e;
}

// ---------------- K1: fused prep + gx precompute ---------------------------
#define WPACKS (5 * KP)
#define PREPBLKS (WPACKS + G4)
__global__ void k_lstm_pre(const float* __restrict__ x,
                           const float* __restrict__ Wi_f, const float* __restrict__ b_f,
                           const float* __restrict__ Wi_b, const float* __restrict__ b_b,
                           float* __restrict__ gx,
                           const float* __restrict__ W1, const float* __restrict__ W2,
                           const float* __restrict__ b1,
                           const float* __restrict__ Wh_f, const float* __restrict__ Wh_b,
                           const float* __restrict__ Wc1, const float* __restrict__ Wb1,
                           const float* __restrict__ bc1, const float* __restrict__ bb1,
                           short* __restrict__ wfC, short* __restrict__ wfD,
                           short* __restrict__ wfE, short* __restrict__ wfHC,
                           short* __restrict__ wfHB,
                           float* __restrict__ w2p, float* __restrict__ b1p,
                           float* __restrict__ bc1p, float* __restrict__ bb1p,
                           __half* __restrict__ whp) {
    int blk0 = blockIdx.x;
    int tid = threadIdx.x;
    if (blk0 < WPACKS) {
        int which = blk0 / KP;
        int k = blk0 % KP;
        float w = 0.f;
        short* dst = wfC;
        if (which == 0)      { if (k < KH) w = W1[k * (3 * FF) + tid];          dst = wfC; }
        else if (which == 1) { if (k < KH) w = W1[k * (3 * FF) + FF + tid];     dst = wfD; }
        else if (which == 2) { if (k < KH) w = W1[k * (3 * FF) + 2 * FF + tid]; dst = wfE; }
        else if (which == 3) { if (k < KH) w = Wc1[k * FF + tid];               dst = wfHC; }
        else                 { if (k < KH) w = Wb1[k * FF + tid];               dst = wfHB; }
        dst[fragidx(k, tid)] = (short)f2bf(w);
        if (tid == 0) {
            if (which == 0) {
                w2p[k] = (k < KH) ? W2[k] : 0.f;
                b1p[k] = (k < KH) ? b1[k] : 0.f;
            } else if (which == 3) {
                bc1p[k] = (k < KH) ? bc1[k] : 0.f;
            } else if (which == 4) {
                bb1p[k] = (k < KH) ? bb1[k] : 0.f;
            }
        }
        return;
    }
    if (blk0 < PREPBLKS) {
        // Pack Wh into fp16 MFMA B-fragments for mfma_f32_16x16x32_f16.
        int gq = blk0 - WPACKS;          // 0..511 = gate*128 + unit
        int gate = gq >> 7;
        int unit = gq & 127;
        int wv = unit >> 4, col = unit & 15;
        int dir = tid >> 7, k = tid & 127;
        int kt = k >> 5, lanehi = (k >> 3) & 3, e = k & 7;
        int lane = lanehi * 16 + col;
        const float* Wh = dir ? Wh_b : Wh_f;
        whp[(size_t)(((((dir * 4 + gate) * 8 + wv) * 4 + kt) * 64) + lane) * 8 + e] =
            (__half)Wh[gq * HH + k];
        return;
    }
    int blk = blk0 - PREPBLKS;         // db*S + t
    int t = blk % SS;
    int db = blk / SS;                 // dir*2 + b
    int b = db & 1, dir = db >> 1;
    const float* Wi = dir ? Wi_b : Wi_f;
    const float* bias = dir ? b_b : b_f;
    int xt = dir ? (SS - 1 - t) : t;

    __shared__ __align__(16) float xr[II];
    if (tid < II) xr[tid] = x[(b * SS + xt) * II + tid];
    __syncthreads();

    for (int g = tid; g < G4; g += 256) {
        const float* w = Wi + g * II;
        float acc = bias[g];
#pragma unroll
        for (int i = 0; i < II; i += 4) {
            float4 w4 = *(const float4*)(w + i);
            acc += w4.x * xr[i] + w4.y * xr[i + 1] + w4.z * xr[i + 2] + w4.w * xr[i + 3];
        }
        // layout [db][t][unit][gate] so rec reads one float4 per lane
        gx[((size_t)(db * SS + t) * HH + (g & 127)) * 4 + (g >> 7)] = acc;
    }
}

// ---------------- K2: recurrent LSTM v8 — depth-2 MFMA chains --------------
// r8: rec sticky at 214 µs = 1286 cy/step vs ~600 model; biggest modellable
// residue = dependent-MFMA latency (4-deep chain, ~30-60 cy each). v8 splits
// each gate's K-accumulation into TWO depth-2 chains + scalar add:
// p=mfma(a0,b0)->mfma(a2,b2,p); q=mfma(a1,b1)->mfma(a3,b3,q); y=p[0]+q[0].
// Same 32 MFMA issued; serial depth 4L -> 2L+add.
__global__ __launch_bounds__(256, 1)
void k_lstm_rec(const _Float16* __restrict__ whf, const float* __restrict__ gxr,
                float* __restrict__ rnn_out) {
    int db = blockIdx.x;
    int b = db & 1, dir = db >> 1;
    int tid = threadIdx.x;
    int wv = tid >> 6;              // 0..3
    int lane = tid & 63;

    // B frags for the wave's two 16-unit groups (packed groups 2wv, 2wv+1)
    f16x8 bfA[4][4], bfB[4][4];
    {
        const f16x8* wp = (const f16x8*)whf;
#pragma unroll
        for (int g = 0; g < 4; ++g)
#pragma unroll
            for (int kt = 0; kt < 4; ++kt) {
                bfA[g][kt] = wp[((((dir * 4 + g) * 8 + (2 * wv)) * 4 + kt) * 64) + lane];
                bfB[g][kt] = wp[((((dir * 4 + g) * 8 + (2 * wv + 1)) * 4 + kt) * 64) + lane];
            }
    }

    __shared__ __align__(16) __half hsf[2][128];
    (&hsf[0][0])[tid] = (__half)0.f;           // 256 entries, 256 threads
    __syncthreads();

    bool act = (lane < 32);
    bool grpB = (lane >= 16);                  // within act: group select
    int unit = (wv << 5) + (lane & 31);        // valid for act lanes
    float c_state = 0.f;

    const float4* gp4 = (const float4*)gxr + (size_t)(db * SS) * HH + unit;
    float4 g0 = make_float4(0,0,0,0), g1 = g0, g2 = g0, g3 = g0;
    if (act) {
        g0 = gp4[0 * HH];
        g1 = gp4[1 * HH];
        g2 = gp4[2 * HH];
        g3 = gp4[3 * HH];
    }
    const float4* gq = gp4 + (size_t)4 * HH;   // marching prefetch cursor

    float* outp = rnn_out + ((size_t)b * SS + (dir ? (SS - 1) : 0)) * FF
                + dir * HH + unit;             // consumed only by act lanes
    const int ostep = dir ? -FF : FF;

    const f32x4 z4 = (f32x4){0.f, 0.f, 0.f, 0.f};
    int pb = 0;
    int hib = (lane >> 4) * 8;                 // k-chunk base within ktile
    bool aload = (lane & 3) == 0;              // A rows 0,4,8,12 hold h

    f16x8 a0v = (f16x8)(_Float16)0.f, a1v = a0v, a2v = a0v, a3v = a0v;

#define REC_STEP(G, PF) do {                                                   \
        if (aload) {                                                           \
            a0v = *(const f16x8*)(&hsf[pb][ 0 + hib]);                         \
            a1v = *(const f16x8*)(&hsf[pb][32 + hib]);                         \
            a2v = *(const f16x8*)(&hsf[pb][64 + hib]);                         \
            a3v = *(const f16x8*)(&hsf[pb][96 + hib]);                         \
        }                                                                      \
        /* two depth-2 chains per (group, gate): p uses kt 0,2; q uses 1,3 */  \
        f32x4 pA0 = __builtin_amdgcn_mfma_f32_16x16x32_f16(a0v, bfA[0][0], z4, 0, 0, 0); \
        f32x4 pA1 = __builtin_amdgcn_mfma_f32_16x16x32_f16(a0v, bfA[1][0], z4, 0, 0, 0); \
        f32x4 pA2 = __builtin_amdgcn_mfma_f32_16x16x32_f16(a0v, bfA[2][0], z4, 0, 0, 0); \
        f32x4 pA3 = __builtin_amdgcn_mfma_f32_16x16x32_f16(a0v, bfA[3][0], z4, 0, 0, 0); \
        f32x4 pB0 = __builtin_amdgcn_mfma_f32_16x16x32_f16(a0v, bfB[0][0], z4, 0, 0, 0); \
        f32x4 pB1 = __builtin_amdgcn_mfma_f32_16x16x32_f16(a0v, bfB[1][0], z4, 0, 0, 0); \
        f32x4 pB2 = __builtin_amdgcn_mfma_f32_16x16x32_f16(a0v, bfB[2][0], z4, 0, 0, 0); \
        f32x4 pB3 = __builtin_amdgcn_mfma_f32_16x16x32_f16(a0v, bfB[3][0], z4, 0, 0, 0); \
        f32x4 qA0 = __builtin_amdgcn_mfma_f32_16x16x32_f16(a1v, bfA[0][1], z4, 0, 0, 0); \
        f32x4 qA1 = __builtin_amdgcn_mfma_f32_16x16x32_f16(a1v, bfA[1][1], z4, 0, 0, 0); \
        f32x4 qA2 = __builtin_amdgcn_mfma_f32_16x16x32_f16(a1v, bfA[2][1], z4, 0, 0, 0); \
        f32x4 qA3 = __builtin_amdgcn_mfma_f32_16x16x32_f16(a1v, bfA[3][1], z4, 0, 0, 0); \
        f32x4 qB0 = __builtin_amdgcn_mfma_f32_16x16x32_f16(a1v, bfB[0][1], z4, 0, 0, 0); \
        f32x4 qB1 = __builtin_amdgcn_mfma_f32_16x16x32_f16(a1v, bfB[1][1], z4, 0, 0, 0); \
        f32x4 qB2 = __builtin_amdgcn_mfma_f32_16x16x32_f16(a1v, bfB[2][1], z4, 0, 0, 0); \
        f32x4 qB3 = __builtin_amdgcn_mfma_f32_16x16x32_f16(a1v, bfB[3][1], z4, 0, 0, 0); \
        pA0 = __builtin_amdgcn_mfma_f32_16x16x32_f16(a2v, bfA[0][2], pA0, 0, 0, 0); \
        pA1 = __builtin_amdgcn_mfma_f32_16x16x32_f16(a2v, bfA[1][2], pA1, 0, 0, 0); \
        pA2 = __builtin_amdgcn_mfma_f32_16x16x32_f16(a2v, bfA[2][2], pA2, 0, 0, 0); \
        pA3 = __builtin_amdgcn_mfma_f32_16x16x32_f16(a2v, bfA[3][2], pA3, 0, 0, 0); \
        pB0 = __builtin_amdgcn_mfma_f32_16x16x32_f16(a2v, bfB[0][2], pB0, 0, 0, 0); \
        pB1 = __builtin_amdgcn_mfma_f32_16x16x32_f16(a2v, bfB[1][2], pB1, 0, 0, 0); \
        pB2 = __builtin_amdgcn_mfma_f32_16x16x32_f16(a2v, bfB[2][2], pB2, 0, 0, 0); \
        pB3 = __builtin_amdgcn_mfma_f32_16x16x32_f16(a2v, bfB[3][2], pB3, 0, 0, 0); \
        qA0 = __builtin_amdgcn_mfma_f32_16x16x32_f16(a3v, bfA[0][3], qA0, 0, 0, 0); \
        qA1 = __builtin_amdgcn_mfma_f32_16x16x32_f16(a3v, bfA[1][3], qA1, 0, 0, 0); \
        qA2 = __builtin_amdgcn_mfma_f32_16x16x32_f16(a3v, bfA[2][3], qA2, 0, 0, 0); \
        qA3 = __builtin_amdgcn_mfma_f32_16x16x32_f16(a3v, bfA[3][3], qA3, 0, 0, 0); \
        qB0 = __builtin_amdgcn_mfma_f32_16x16x32_f16(a3v, bfB[0][3], qB0, 0, 0, 0); \
        qB1 = __builtin_amdgcn_mfma_f32_16x16x32_f16(a3v, bfB[1][3], qB1, 0, 0, 0); \
        qB2 = __builtin_amdgcn_mfma_f32_16x16x32_f16(a3v, bfB[2][3], qB2, 0, 0, 0); \
        qB3 = __builtin_amdgcn_mfma_f32_16x16x32_f16(a3v, bfB[3][3], qB3, 0, 0, 0); \
        if (act) {                                                             \
            float y0 = grpB ? (pB0[0] + qB0[0]) : (pA0[0] + qA0[0]);           \
            float y1 = grpB ? (pB1[0] + qB1[0]) : (pA1[0] + qA1[0]);           \
            float y2 = grpB ? (pB2[0] + qB2[0]) : (pA2[0] + qA2[0]);           \
            float y3 = grpB ? (pB3[0] + qB3[0]) : (pA3[0] + qA3[0]);           \
            float gi = y0 + G.x;                                               \
            float gf = y1 + G.y;                                               \
            float gg = y2 + G.z;                                               \
            float go = y3 + G.w;                                               \
            if (PF) { G = *gq; gq += HH; }    /* reissue prefetch (t+4) */     \
            c_state = fast_sigmoid(gf) * c_state + fast_sigmoid(gi) * fast_tanh(gg); \
            float h = fast_sigmoid(go) * fast_tanh(c_state);                   \
            hsf[pb ^ 1][unit] = (__half)h;                                     \
            *outp = h;                                                         \
            outp += ostep;                                                     \
        }                                                                      \
        rec_barrier();                                                         \
        pb ^= 1;                                                               \
    } while (0)

    for (int it = 0; it < 99; ++it) {          // steps 0..395, prefetch valid
        REC_STEP(g0, 1);
        REC_STEP(g1, 1);
        REC_STEP(g2, 1);
        REC_STEP(g3, 1);
    }
    // epilogue: steps 396..399, no prefetch
    REC_STEP(g0, 0);
    REC_STEP(g1, 0);
    REC_STEP(g2, 0);
    REC_STEP(g3, 0);
#undef REC_STEP
}

// ---------------- K4: fused cum (blocks 0..1) + MFMA mlp (blocks 2..52) ----
// cum and mlp both depend only on rnn; k_scores consumes both outputs.
// Fusing saves a launch gap and hides cum's ~12 µs under mlp.
#define PXBLKS 26
#define HDBLKS 25
#define AP 272          // k_mlp A-tile row stride in shorts
#define UCP 116         // uc tile row stride in floats
__global__ __launch_bounds__(256, 2)
void k_cum_mlp(const float* __restrict__ rnn, float* __restrict__ cum,
               const float* __restrict__ a1p,
               const float* __restrict__ ac1p, const float* __restrict__ ab1p,
               const short* __restrict__ wfD, const short* __restrict__ wfE,
               const short* __restrict__ wfHC, const short* __restrict__ wfHB,
               const float* __restrict__ bc1p, const float* __restrict__ bb1p,
               const float* __restrict__ ac2p, const float* __restrict__ ab2p,
               const float* __restrict__ Wc2, const float* __restrict__ bc2,
               const float* __restrict__ Wb2, const float* __restrict__ bb2,
               float* __restrict__ pxd, float* __restrict__ pxe,
               float* __restrict__ cls_out, float* __restrict__ bin_out) {
    int tid = threadIdx.x;
    if (blockIdx.x < BB) {
        // ---- cumsum over time: single fused sequential scan
        int b = blockIdx.x;
        int f = tid;                // 256 threads
        float run = 0.f;
        cum[(size_t)(b * NN) * FF + f] = 0.f;      // xp row 0 = zeros
        const float* rp = rnn + (size_t)b * SS * FF + f;
        float* cp = cum + ((size_t)b * NN + 1) * FF + f;
#pragma unroll 8
        for (int t = 0; t < SS; ++t) {
            run += rp[(size_t)t * FF];
            cp[(size_t)t * FF] = run;
        }
        return;
    }
    int blk = blockIdx.x - BB;
    bool is_px = (blk < PXBLKS);
    int rowbase = is_px ? blk * 32 : (blk - PXBLKS) * 32;
    int nrows_tot = is_px ? BB * NN : BB * SS;

    __shared__ __align__(16) short dth[2][32][AP];
    __shared__ float ucsh[2][32][UCP];

    // ---- build A tiles (rows = data rows)
    {
        int row = tid >> 3;
        int fb = (tid & 7) * 32;
        int rg = rowbase + row;
        float src[32];
        if (is_px) {
            float a1 = a1p[0];
            int b = rg / NN, n = rg % NN;
            bool valid = (rg < nrows_tot) && (n > 0);
            const float* sp = valid ? (rnn + (b * SS + n - 1) * FF + fb) : nullptr;
#pragma unroll
            for (int c4 = 0; c4 < 8; ++c4) {
                float4 v = valid ? *(const float4*)(sp + c4 * 4) : make_float4(0,0,0,0);
                src[c4*4] = v.x; src[c4*4+1] = v.y; src[c4*4+2] = v.z; src[c4*4+3] = v.w;
            }
            union { short8 s; unsigned short u[8]; } h8;
#pragma unroll
            for (int c8 = 0; c8 < 4; ++c8) {
#pragma unroll
                for (int e = 0; e < 8; ++e) h8.u[e] = f2bf(prelu_f(src[c8*8+e], a1));
                *(short8*)(&dth[0][row][fb + c8 * 8]) = h8.s;
            }
        } else {
            float ac1 = ac1p[0], ab1 = ab1p[0];
            bool valid = (rg < nrows_tot);
            const float* sp = valid ? (rnn + rg * FF + fb) : nullptr;
#pragma unroll
            for (int c4 = 0; c4 < 8; ++c4) {
                float4 v = valid ? *(const float4*)(sp + c4 * 4) : make_float4(0,0,0,0);
                src[c4*4] = v.x; src[c4*4+1] = v.y; src[c4*4+2] = v.z; src[c4*4+3] = v.w;
            }
            union { short8 s; unsigned short u[8]; } hc, hb;
#pragma unroll
            for (int c8 = 0; c8 < 4; ++c8) {
#pragma unroll
                for (int e = 0; e < 8; ++e) {
                    hc.u[e] = f2bf(prelu_f(src[c8*8+e], ac1));
                    hb.u[e] = f2bf(prelu_f(src[c8*8+e], ab1));
                }
                *(short8*)(&dth[0][row][fb + c8 * 8]) = hc.s;
                *(short8*)(&dth[1][row][fb + c8 * 8]) = hb.s;
            }
        }
    }
    __syncthreads();

    int lane = tid & 63;
    int wv = tid >> 6;
    int quad = lane >> 4;
    int l15 = lane & 15;
    int kt0 = wv * 2, kt1 = wv * 2 + 1;
    bool has1 = (kt1 < 7);

    const short8* wp0 = (const short8*)(is_px ? wfD : wfHC);
    const short8* wp1 = (const short8*)(is_px ? wfE : wfHB);

    // acc[path][mt][kt]
    f32x4 acc[2][2][2];
#pragma unroll
    for (int p = 0; p < 2; ++p)
#pragma unroll
        for (int mt = 0; mt < 2; ++mt)
#pragma unroll
            for (int kk = 0; kk < 2; ++kk) acc[p][mt][kk] = (f32x4){0.f,0.f,0.f,0.f};

#pragma unroll
    for (int ks = 0; ks < 8; ++ks) {
        short8 b00 = wp0[((kt0 * 8 + ks) * 4 + quad) * 16 + l15];
        short8 b01 = has1 ? wp0[((kt1 * 8 + ks) * 4 + quad) * 16 + l15] : b00;
        short8 b10 = wp1[((kt0 * 8 + ks) * 4 + quad) * 16 + l15];
        short8 b11 = has1 ? wp1[((kt1 * 8 + ks) * 4 + quad) * 16 + l15] : b10;
#pragma unroll
        for (int mt = 0; mt < 2; ++mt) {
            short8 a0 = *(const short8*)(&dth[0][mt * 16 + l15][ks * 32 + quad * 8]);
            short8 a1v = is_px ? a0
                       : *(const short8*)(&dth[1][mt * 16 + l15][ks * 32 + quad * 8]);
            acc[0][mt][0] = __builtin_amdgcn_mfma_f32_16x16x32_bf16(a0, b00, acc[0][mt][0], 0, 0, 0);
            acc[1][mt][0] = __builtin_amdgcn_mfma_f32_16x16x32_bf16(a1v, b10, acc[1][mt][0], 0, 0, 0);
            if (has1) {
                acc[0][mt][1] = __builtin_amdgcn_mfma_f32_16x16x32_bf16(a0, b01, acc[0][mt][1], 0, 0, 0);
                acc[1][mt][1] = __builtin_amdgcn_mfma_f32_16x16x32_bf16(a1v, b11, acc[1][mt][1], 0, 0, 0);
            }
        }
    }

    int kout0 = kt0 * 16 + l15;
    int kout1 = has1 ? (kt1 * 16 + l15) : 0;

    if (is_px) {
#pragma unroll
        for (int mt = 0; mt < 2; ++mt) {
#pragma unroll
            for (int r = 0; r < 4; ++r) {
                int m = mt * 16 + quad * 4 + r;
                int rg = rowbase + m;
                if (rg < nrows_tot) {
                    pxd[rg * KP + kout0] = acc[0][mt][0][r];
                    pxe[rg * KP + kout0] = acc[1][mt][0][r];
                    if (has1) {
                        pxd[rg * KP + kout1] = acc[0][mt][1][r];
                        pxe[rg * KP + kout1] = acc[1][mt][1][r];
                    }
                }
            }
        }
        return;
    }

    // heads: layer1 activation -> LDS, then layer2 matvecs
    float bc0 = bc1p[kout0], bc1v = bc1p[kout1];
    float bb0 = bb1p[kout0], bb1v = bb1p[kout1];
    float ac2 = ac2p[0], ab2 = ab2p[0];
#pragma unroll
    for (int mt = 0; mt < 2; ++mt) {
#pragma unroll
        for (int r = 0; r < 4; ++r) {
            int m = mt * 16 + quad * 4 + r;
            ucsh[0][m][kout0] = prelu_f(acc[0][mt][0][r] + bc0, ac2);
            ucsh[1][m][kout0] = prelu_f(acc[1][mt][0][r] + bb0, ab2);
            if (has1) {
                ucsh[0][m][kout1] = prelu_f(acc[0][mt][1][r] + bc1v, ac2);
                ucsh[1][m][kout1] = prelu_f(acc[1][mt][1][r] + bb1v, ab2);
            }
        }
    }
    __syncthreads();
    {
        int row = tid >> 3;
        int oc = tid & 7;
        int rg = rowbase + row;
        bool valid = (rg < nrows_tot);
        for (int o = oc; o < NCLS; o += 8) {
            float s = bc2[o];
            const float* w = Wc2 + o * KH;
#pragma unroll 4
            for (int k = 0; k < KH; ++k) s += w[k] * ucsh[0][row][k];
            if (valid) cls_out[rg * NCLS + o] = s;
        }
        // bin: 32 rows x 2 outputs = 64 work items
        if (tid < 64) {
            int row2 = tid >> 1, o = tid & 1;
            int rg2 = rowbase + row2;
            float s = bb2[o];
            const float* w = Wb2 + o * KH;
#pragma unroll 4
            for (int k = 0; k < KH; ++k) s += w[k] * ucsh[1][row2][k];
            if (rg2 < nrows_tot) bin_out[rg2 * 2 + o] = s;
        }
    }
}

// ---------------- K5: scores — conflict-fixed LDS layouts ------------------
#define JT 32
#define JTILES 13
#define NP2 201
#define APS 280         // k_scores A-tile row stride in shorts
#define CIP 264         // padded cish row: FF + FF/32
__global__ __launch_bounds__(256, 3)
void k_scores(const float* __restrict__ cum,
              const short* __restrict__ wfrag,
              const float* __restrict__ pxd, const float* __restrict__ pxe,
              const float* __restrict__ b1p, const float* __restrict__ w2p,
              const float* __restrict__ b2p,
              const float* __restrict__ a1p, const float* __restrict__ a2p,
              float* __restrict__ scores, float* __restrict__ dpcol) {
    int blk = blockIdx.x;
    int jt = blk % JTILES;
    int ipair = (blk / JTILES) % NP2;
    int b = blk / (JTILES * NP2);
    int tid = threadIdx.x;
    float a1 = a1p[0], a2 = a2p[0];
    int jbase = jt * JT;
    int i0 = ipair * 2;
    int i1 = i0 + 1;
    bool has_i1 = (i1 <= SS);
    int i1c = has_i1 ? i1 : i0;

    __shared__ __align__(16) float cish[2][CIP];
    __shared__ __align__(16) short dth[2][JT][APS];
    __shared__ float red[2][4][JT];

    cish[0][tid + (tid >> 5)] = cum[(b * NN + i0) * FF + tid];
    cish[1][tid + (tid >> 5)] = cum[(b * NN + i1c) * FF + tid];
    __syncthreads();

    {
        int row = tid >> 3;
        int fb = (tid & 7) * 32;
        int fbq = fb + (tid & 7);       // padded cish base for this chunk
        int jg = jbase + row;
        int jc = (jg <= SS) ? jg : SS;
        const float* cj = cum + (b * NN + jc) * FF + fb;
        float4 v[8];
#pragma unroll
        for (int c8 = 0; c8 < 4; ++c8) {
            v[2 * c8] = *(const float4*)(cj + c8 * 8);
            v[2 * c8 + 1] = *(const float4*)(cj + c8 * 8 + 4);
        }
#pragma unroll
        for (int ii = 0; ii < 2; ++ii) {
            const float* cio = &cish[ii][0];
#pragma unroll
            for (int c8 = 0; c8 < 4; ++c8) {
                float dv[8] = { v[2*c8].x, v[2*c8].y, v[2*c8].z, v[2*c8].w,
                                v[2*c8+1].x, v[2*c8+1].y, v[2*c8+1].z, v[2*c8+1].w };
                union { short8 s; unsigned short u[8]; } h8;
#pragma unroll
                for (int e = 0; e < 8; ++e) {
                    float d = prelu_f(dv[e] - cio[fbq + c8 * 8 + e], a1);
                    h8.u[e] = f2bf(d);
                }
                *(short8*)(&dth[ii][row][fb + c8 * 8]) = h8.s;
            }
        }
    }
    __syncthreads();

    int lane = tid & 63;
    int wv = tid >> 6;
    int quad = lane >> 4;
    int l15 = lane & 15;
    int kt0 = wv * 2, kt1 = wv * 2 + 1;
    bool has1 = (kt1 < 7);

    const short8* wf = (const short8*)wfrag;
    f32x4 acc[2][2][2];
#pragma unroll
    for (int ii = 0; ii < 2; ++ii)
#pragma unroll
        for (int mt = 0; mt < 2; ++mt)
#pragma unroll
            for (int kk = 0; kk < 2; ++kk) acc[ii][mt][kk] = (f32x4){0.f,0.f,0.f,0.f};

#pragma unroll
    for (int ks = 0; ks < 8; ++ks) {
        short8 b0 = wf[((kt0 * 8 + ks) * 4 + quad) * 16 + l15];
        short8 b1v = has1 ? wf[((kt1 * 8 + ks) * 4 + quad) * 16 + l15] : b0;
#pragma unroll
        for (int ii = 0; ii < 2; ++ii) {
#pragma unroll
            for (int mt = 0; mt < 2; ++mt) {
                short8 a = *(const short8*)(&dth[ii][mt * 16 + l15][ks * 32 + quad * 8]);
                acc[ii][mt][0] = __builtin_amdgcn_mfma_f32_16x16x32_bf16(a, b0, acc[ii][mt][0], 0, 0, 0);
                if (has1)
                    acc[ii][mt][1] = __builtin_amdgcn_mfma_f32_16x16x32_bf16(a, b1v, acc[ii][mt][1], 0, 0, 0);
            }
        }
    }

    int kout0 = kt0 * 16 + l15;
    int kout1 = has1 ? (kt1 * 16 + l15) : 0;
    float bb0 = b1p[kout0], bb1v = b1p[kout1];
    float w20 = w2p[kout0];
    float w21 = has1 ? w2p[kout1] : 0.f;

#pragma unroll
    for (int ii = 0; ii < 2; ++ii) {
        int iv = ii ? i1c : i0;
        float pd0 = pxd[(b * NN + iv) * KP + kout0];
        float pd1 = pxd[(b * NN + iv) * KP + kout1];
#pragma unroll
        for (int mt = 0; mt < 2; ++mt) {
#pragma unroll
            for (int r = 0; r < 4; ++r) {
                int m = mt * 16 + quad * 4 + r;
                int jg = jbase + m;
                int jc = (jg <= SS) ? jg : SS;
                float pe0 = pxe[(b * NN + jc) * KP + kout0];
                float pe1 = pxe[(b * NN + jc) * KP + kout1];
                float h0 = acc[ii][mt][0][r] + pd0 + pe0 + bb0;
                float s = w20 * prelu_f(h0, a2);
                float h1 = acc[ii][mt][1][r] + pd1 + pe1 + bb1v;
                s += w21 * prelu_f(h1, a2);
                s += __shfl_xor(s, 1);
                s += __shfl_xor(s, 2);
                s += __shfl_xor(s, 4);
                s += __shfl_xor(s, 8);
                if (l15 == 0) red[ii][wv][m] = s;
            }
        }
    }
    __syncthreads();
    if (tid < 2 * JT) {
        int ii = tid >> 5;
        int jl = tid & 31;
        int jg = jbase + jl;
        int iv = ii ? i1 : i0;
        if (jg <= SS && (ii == 0 || has_i1)) {
            float tot = red[ii][0][jl] + red[ii][1][jl] + red[ii][2][jl] + red[ii][3][jl] + b2p[0];
            scores[(b * NN + iv) * NN + jg] = tot;
            int d = jg - iv;
            if (d >= 1 && d <= MAXSEG) {
                // rotating-slot layout: slot = iv mod 64 (window<64 => injective)
                dpcol[(b * NN + jg) * 64 + (iv & 63)] = tot;
            }
        }
    }
}

// ---------------- K7: DP v3 — max-only DPP + ballot argmax -----------------
__global__ void k_dp(const float* __restrict__ dpcol, const int* __restrict__ lengths,
                     float* __restrict__ predF, float* __restrict__ prevF) {
    int b = blockIdx.x;
    int lane = threadIdx.x;          // 64 threads = 1 wave
    int len = lengths[b];
    if (lane == 0) prevF[b * NN] = 0.f;

    float blr = 0.f;                 // lane l holds best[k] for latest k ≡ l (mod 64)
    float predv = 0.f;

#define LO(I) (((I) > MAXSEG) ? ((I) - MAXSEG) : 0)
#define LOADCOL(ii) \
    ( ((ii) <= SS && (((lane - LO(ii)) & 63) < ((ii) - LO(ii)))) \
        ? dpcol[(b * NN + (ii)) * 64 + lane] : 0.f )

    float u0 = LOADCOL(1), u1 = LOADCOL(2), u2 = LOADCOL(3), u3 = LOADCOL(4);
    float u4 = LOADCOL(5), u5 = LOADCOL(6), u6 = LOADCOL(7), u7 = LOADCOL(8);

#define DPP_MAX(CTRL, v) do {                                                 \
        int _t = __builtin_amdgcn_update_dpp(__float_as_int(v),               \
                     __float_as_int(v), (CTRL), 0xF, 0xF, false);             \
        (v) = fmaxf((v), __int_as_float(_t));                                 \
    } while (0)

#define DP_STEP(I, BUF) do {                                                  \
        int lo_ = LO(I);                                                      \
        int cnt_ = (I) - lo_;                                                 \
        int off_ = (lane - lo_) & 63;                                         \
        float v0_ = (off_ < cnt_) ? blr + BUF : -INFINITY;                    \
        float v_ = v0_;                                                       \
        DPP_MAX(0x111, v_);   /* row_shr:1  */                                \
        DPP_MAX(0x112, v_);   /* row_shr:2  */                                \
        DPP_MAX(0x114, v_);   /* row_shr:4  */                                \
        DPP_MAX(0x118, v_);   /* row_shr:8  */                                \
        DPP_MAX(0x142, v_);   /* row_bcast:15 */                              \
        DPP_MAX(0x143, v_);   /* row_bcast:31 */                              \
        float m_ = __int_as_float(                                            \
            __builtin_amdgcn_readlane(__float_as_int(v_), 63));               \
        unsigned long long mk_ = __ballot(v0_ == m_);                         \
        int rot_ = lo_ & 63;                                                  \
        unsigned long long mr_ = rot_ ? ((mk_ >> rot_) | (mk_ << (64 - rot_))) \
                                      : mk_;                                  \
        int kb_ = lo_ + (__ffsll(mr_) - 1);                                   \
        if (lane == 0) {                                                      \
            prevF[b * NN + (I)] = (float)kb_;                                 \
            if ((I) == len) predv = m_;                                       \
        }                                                                     \
        if (lane == ((I) & 63)) blr = m_;                                     \
    } while (0)

    for (int i = 1; i <= SS; i += 8) {
        DP_STEP(i, u0);     u0 = LOADCOL(i + 8);
        DP_STEP(i + 1, u1); u1 = LOADCOL(i + 9);
        DP_STEP(i + 2, u2); u2 = LOADCOL(i + 10);
        DP_STEP(i + 3, u3); u3 = LOADCOL(i + 11);
        DP_STEP(i + 4, u4); u4 = LOADCOL(i + 12);
        DP_STEP(i + 5, u5); u5 = LOADCOL(i + 13);
        DP_STEP(i + 6, u6); u6 = LOADCOL(i + 14);
        DP_STEP(i + 7, u7); u7 = LOADCOL(i + 15);
    }
#undef DP_STEP
#undef DPP_MAX
#undef LOADCOL
#undef LO
    if (lane == 0) predF[b] = predv;
}

// ---------------- launch ---------------------------------------------------
extern "C" void kernel_launch(void* const* d_in, const int* in_sizes, int n_in,
                              void* d_out, int out_size, void* d_ws, size_t ws_size,
                              hipStream_t stream) {
    const float* x    = (const float*)d_in[0];
    const int* lengths= (const int*)d_in[1];
    const float* Wi_f = (const float*)d_in[2];
    const float* Wh_f = (const float*)d_in[3];
    const float* b_f  = (const float*)d_in[4];
    const float* Wi_b = (const float*)d_in[5];
    const float* Wh_b = (const float*)d_in[6];
    const float* b_b  = (const float*)d_in[7];
    const float* a1   = (const float*)d_in[8];
    const float* W1   = (const float*)d_in[9];
    const float* b1   = (const float*)d_in[10];
    const float* a2   = (const float*)d_in[11];
    const float* W2   = (const float*)d_in[12];
    const float* b2   = (const float*)d_in[13];
    const float* ac1  = (const float*)d_in[14];
    const float* Wc1  = (const float*)d_in[15];
    const float* bc1  = (const float*)d_in[16];
    const float* ac2  = (const float*)d_in[17];
    const float* Wc2  = (const float*)d_in[18];
    const float* bc2  = (const float*)d_in[19];
    const float* ab1  = (const float*)d_in[20];
    const float* Wb1  = (const float*)d_in[21];
    const float* bb1  = (const float*)d_in[22];
    const float* ab2  = (const float*)d_in[23];
    const float* Wb2  = (const float*)d_in[24];
    const float* bb2  = (const float*)d_in[25];

    float* out = (float*)d_out;
    float* scores = out + SCORES_OFF;
    float* cls    = out + CLS_OFF;
    float* bin    = out + BIN_OFF;
    float* pred   = out + PRED_OFF;
    float* prev   = out + PREV_OFF;

    float* ws    = (float*)d_ws;
    float* gx    = ws + WS_GX;
    float* dpcol = ws + WS_GX;       // reuse: gx dead after k_lstm_rec
    float* rnn   = ws + WS_RNN;
    float* cum   = ws + WS_CUM;
    float* pxd   = ws + WS_PXD;
    float* pxe   = ws + WS_PXE;
    float* w2p   = ws + WS_W2P;
    float* b1p   = ws + WS_B1P;
    __half* whp  = (__half*)(ws + WS_WHP);
    short* wfC   = (short*)(ws + WS_WFRAGC);
    short* wfD   = (short*)(ws + WS_WFRAGD);
    short* wfE   = (short*)(ws + WS_WFRAGE);
    short* wfHC  = (short*)(ws + WS_WFRAGHC);
    short* wfHB  = (short*)(ws + WS_WFRAGHB);
    float* bc1p  = ws + WS_BC1P;
    float* bb1p  = ws + WS_BB1P;

    k_lstm_pre<<<PREPBLKS + 4 * SS, 256, 0, stream>>>(x, Wi_f, b_f, Wi_b, b_b, gx,
                                                      W1, W2, b1, Wh_f, Wh_b,
                                                      Wc1, Wb1, bc1, bb1,
                                                      wfC, wfD, wfE, wfHC, wfHB,
                                                      w2p, b1p, bc1p, bb1p, whp);
    k_lstm_rec<<<4, 256, 0, stream>>>((const _Float16*)whp, gx, rnn);
    k_cum_mlp<<<BB + PXBLKS + HDBLKS, 256, 0, stream>>>(rnn, cum, a1, ac1, ab1,
                                                        wfD, wfE, wfHC, wfHB,
                                                        bc1p, bb1p, ac2, ab2,
                                                        Wc2, bc2, Wb2, bb2,
                                                        pxd, pxe, cls, bin);
    k_scores<<<BB * NP2 * JTILES, 256, 0, stream>>>(cum, wfC, pxd, pxe, b1p, w2p, b2,
                                                    a1, a2, scores, dpcol);
    k_dp<<<BB, 64, 0, stream>>>(dpcol, lengths, pred, prev);
}

// Round 10
// 553.900 us; speedup vs baseline: 1.0474x; 1.0474x over previous
//
#include <hip/hip_runtime.h>
#include <hip/hip_fp16.h>
#include <math.h>

// Problem constants
#define BB 2
#define SS 400
#define II 80
#define HH 128
#define FF 256          // 2*H
#define NN 401          // S+1
#define G4 512          // 4*H
#define MAXSEG 50
#define NCLS 50
#define KH 100          // rows of W1 / Wc1 / Wb1
#define KP 112          // KH padded to 7*16 for MFMA
#define FRAGF 14336     // floats per frag-packed W (28672 shorts)

// d_out layout (floats): scores | cls | bin | pred | prev
#define SCORES_OFF 0
#define CLS_OFF    (BB*NN*NN)
#define BIN_OFF    (CLS_OFF + BB*SS*NCLS)
#define PRED_OFF   (BIN_OFF + BB*SS*2)
#define PREV_OFF   (PRED_OFF + BB)

// workspace layout (float slots)
#define WS_GX      0                          // 819200; dead after rec -> dpcol (51328)
#define WS_RNN     (WS_GX + 4*SS*G4)          // B*S*F
#define WS_CUM     (WS_RNN + BB*SS*FF)        // B*N*F
#define WS_PXD     (WS_CUM + BB*NN*FF)        // B*N*KP
#define WS_PXE     (WS_PXD + BB*NN*KP)
#define WS_PART    (WS_PXE + BB*NN*KP)        // B*16*F (unused since cum fusion)
#define WS_W2P     (WS_PART + BB*16*FF)       // KP
#define WS_B1P     (WS_W2P + KP)              // KP
#define WS_WHP     (WS_B1P + KP)              // Wh f16 MFMA frags: 131072 halfs
#define WS_WFRAGC  (WS_WHP + 65536)
#define WS_WFRAGD  (WS_WFRAGC + FRAGF)
#define WS_WFRAGE  (WS_WFRAGD + FRAGF)
#define WS_WFRAGHC (WS_WFRAGE + FRAGF)
#define WS_WFRAGHB (WS_WFRAGHC + FRAGF)
#define WS_BC1P    (WS_WFRAGHB + FRAGF)       // KP
#define WS_BB1P    (WS_BC1P + KP)             // KP

typedef __attribute__((ext_vector_type(8))) short short8;
typedef __attribute__((ext_vector_type(4))) float f32x4;
typedef _Float16 f16x2 __attribute__((ext_vector_type(2)));
typedef _Float16 f16x8 __attribute__((ext_vector_type(8)));

__device__ __forceinline__ float prelu_f(float x, float a) {
    return x >= 0.f ? x : a * x;
}
__device__ __forceinline__ unsigned short f2bf(float x) {
    union { float f; unsigned u; } v; v.f = x;
    unsigned r = v.u + 0x7fffu + ((v.u >> 16) & 1u);   // RNE
    return (unsigned short)(r >> 16);
}
__device__ __forceinline__ float fast_sigmoid(float x) {
    return 1.f / (1.f + __expf(-x));
}
__device__ __forceinline__ float fast_tanh(float x) {
    return 1.f - 2.f / (1.f + __expf(2.f * x));
}
__device__ __forceinline__ void barrier_lds() {
    asm volatile("s_waitcnt lgkmcnt(0)\ns_barrier" ::: "memory");
}
// m201-style barrier: LDS drained, but vmcnt (global loads/stores) stays
// in flight across the barrier — no "memory" clobber, no vmcnt drain.
__device__ __forceinline__ void rec_barrier() {
    __builtin_amdgcn_sched_barrier(0);
    asm volatile("s_waitcnt lgkmcnt(0)");
    __builtin_amdgcn_s_barrier();
    __builtin_amdgcn_sched_barrier(0);
}
__device__ __forceinline__ int fragidx(int k, int f) {
    int kt = k >> 4, l15 = k & 15;
    int ks = f >> 5, quad = (f >> 3) & 3, e = f & 7;
    return ((((kt * 8 + ks) * 4 + quad) * 16) + l15) * 8 + e;
}

// ---------------- K1: fused prep + gx precompute ---------------------------
#define WPACKS (5 * KP)
#define PREPBLKS (WPACKS + G4)
__global__ void k_lstm_pre(const float* __restrict__ x,
                           const float* __restrict__ Wi_f, const float* __restrict__ b_f,
                           const float* __restrict__ Wi_b, const float* __restrict__ b_b,
                           float* __restrict__ gx,
                           const float* __restrict__ W1, const float* __restrict__ W2,
                           const float* __restrict__ b1,
                           const float* __restrict__ Wh_f, const float* __restrict__ Wh_b,
                           const float* __restrict__ Wc1, const float* __restrict__ Wb1,
                           const float* __restrict__ bc1, const float* __restrict__ bb1,
                           short* __restrict__ wfC, short* __restrict__ wfD,
                           short* __restrict__ wfE, short* __restrict__ wfHC,
                           short* __restrict__ wfHB,
                           float* __restrict__ w2p, float* __restrict__ b1p,
                           float* __restrict__ bc1p, float* __restrict__ bb1p,
                           __half* __restrict__ whp) {
    int blk0 = blockIdx.x;
    int tid = threadIdx.x;
    if (blk0 < WPACKS) {
        int which = blk0 / KP;
        int k = blk0 % KP;
        float w = 0.f;
        short* dst = wfC;
        if (which == 0)      { if (k < KH) w = W1[k * (3 * FF) + tid];          dst = wfC; }
        else if (which == 1) { if (k < KH) w = W1[k * (3 * FF) + FF + tid];     dst = wfD; }
        else if (which == 2) { if (k < KH) w = W1[k * (3 * FF) + 2 * FF + tid]; dst = wfE; }
        else if (which == 3) { if (k < KH) w = Wc1[k * FF + tid];               dst = wfHC; }
        else                 { if (k < KH) w = Wb1[k * FF + tid];               dst = wfHB; }
        dst[fragidx(k, tid)] = (short)f2bf(w);
        if (tid == 0) {
            if (which == 0) {
                w2p[k] = (k < KH) ? W2[k] : 0.f;
                b1p[k] = (k < KH) ? b1[k] : 0.f;
            } else if (which == 3) {
                bc1p[k] = (k < KH) ? bc1[k] : 0.f;
            } else if (which == 4) {
                bb1p[k] = (k < KH) ? bb1[k] : 0.f;
            }
        }
        return;
    }
    if (blk0 < PREPBLKS) {
        // Pack Wh into fp16 MFMA B-fragments for mfma_f32_16x16x32_f16.
        int gq = blk0 - WPACKS;          // 0..511 = gate*128 + unit
        int gate = gq >> 7;
        int unit = gq & 127;
        int wv = unit >> 4, col = unit & 15;
        int dir = tid >> 7, k = tid & 127;
        int kt = k >> 5, lanehi = (k >> 3) & 3, e = k & 7;
        int lane = lanehi * 16 + col;
        const float* Wh = dir ? Wh_b : Wh_f;
        whp[(size_t)(((((dir * 4 + gate) * 8 + wv) * 4 + kt) * 64) + lane) * 8 + e] =
            (__half)Wh[gq * HH + k];
        return;
    }
    int blk = blk0 - PREPBLKS;         // db*S + t
    int t = blk % SS;
    int db = blk / SS;                 // dir*2 + b
    int b = db & 1, dir = db >> 1;
    const float* Wi = dir ? Wi_b : Wi_f;
    const float* bias = dir ? b_b : b_f;
    int xt = dir ? (SS - 1 - t) : t;

    __shared__ __align__(16) float xr[II];
    if (tid < II) xr[tid] = x[(b * SS + xt) * II + tid];
    __syncthreads();

    for (int g = tid; g < G4; g += 256) {
        const float* w = Wi + g * II;
        float acc = bias[g];
#pragma unroll
        for (int i = 0; i < II; i += 4) {
            float4 w4 = *(const float4*)(w + i);
            acc += w4.x * xr[i] + w4.y * xr[i + 1] + w4.z * xr[i + 2] + w4.w * xr[i + 3];
        }
        // layout [db][t][unit][gate] so rec reads one float4 per lane
        gx[((size_t)(db * SS + t) * HH + (g & 127)) * 4 + (g >> 7)] = acc;
    }
}

// ---------------- K2: recurrent LSTM v7 — 4 waves, dual-group MFMA ---------
// (exact r7 kernel, measured 214 µs / VGPR 112. r9's depth-2 split regressed
// to 244: at 1 wave/SIMD the 8 depth-4 chains already saturate issue; the
// split only added registers (136) + adds/cndmasks on the serial tail.)
__global__ __launch_bounds__(256, 1)
void k_lstm_rec(const _Float16* __restrict__ whf, const float* __restrict__ gxr,
                float* __restrict__ rnn_out) {
    int db = blockIdx.x;
    int b = db & 1, dir = db >> 1;
    int tid = threadIdx.x;
    int wv = tid >> 6;              // 0..3
    int lane = tid & 63;

    // B frags for the wave's two 16-unit groups (packed groups 2wv, 2wv+1)
    f16x8 bfA[4][4], bfB[4][4];
    {
        const f16x8* wp = (const f16x8*)whf;
#pragma unroll
        for (int g = 0; g < 4; ++g)
#pragma unroll
            for (int kt = 0; kt < 4; ++kt) {
                bfA[g][kt] = wp[((((dir * 4 + g) * 8 + (2 * wv)) * 4 + kt) * 64) + lane];
                bfB[g][kt] = wp[((((dir * 4 + g) * 8 + (2 * wv + 1)) * 4 + kt) * 64) + lane];
            }
    }

    __shared__ __align__(16) __half hsf[2][128];
    (&hsf[0][0])[tid] = (__half)0.f;           // 256 entries, 256 threads
    __syncthreads();

    bool act = (lane < 32);
    bool grpB = (lane >= 16);                  // within act: group select
    int unit = (wv << 5) + (lane & 31);        // valid for act lanes
    float c_state = 0.f;

    const float4* gp4 = (const float4*)gxr + (size_t)(db * SS) * HH + unit;
    float4 g0 = make_float4(0,0,0,0), g1 = g0, g2 = g0, g3 = g0;
    if (act) {
        g0 = gp4[0 * HH];
        g1 = gp4[1 * HH];
        g2 = gp4[2 * HH];
        g3 = gp4[3 * HH];
    }
    const float4* gq = gp4 + (size_t)4 * HH;   // marching prefetch cursor

    float* outp = rnn_out + ((size_t)b * SS + (dir ? (SS - 1) : 0)) * FF
                + dir * HH + unit;             // consumed only by act lanes
    const int ostep = dir ? -FF : FF;

    const f32x4 z4 = (f32x4){0.f, 0.f, 0.f, 0.f};
    int pb = 0;
    int hib = (lane >> 4) * 8;                 // k-chunk base within ktile
    bool aload = (lane & 3) == 0;              // A rows 0,4,8,12 hold h

    f16x8 a0v = (f16x8)(_Float16)0.f, a1v = a0v, a2v = a0v, a3v = a0v;

#define REC_STEP(G, PF) do {                                                   \
        if (aload) {                                                           \
            a0v = *(const f16x8*)(&hsf[pb][ 0 + hib]);                         \
            a1v = *(const f16x8*)(&hsf[pb][32 + hib]);                         \
            a2v = *(const f16x8*)(&hsf[pb][64 + hib]);                         \
            a3v = *(const f16x8*)(&hsf[pb][96 + hib]);                         \
        }                                                                      \
        f32x4 aA0 = __builtin_amdgcn_mfma_f32_16x16x32_f16(a0v, bfA[0][0], z4, 0, 0, 0); \
        f32x4 aA1 = __builtin_amdgcn_mfma_f32_16x16x32_f16(a0v, bfA[1][0], z4, 0, 0, 0); \
        f32x4 aA2 = __builtin_amdgcn_mfma_f32_16x16x32_f16(a0v, bfA[2][0], z4, 0, 0, 0); \
        f32x4 aA3 = __builtin_amdgcn_mfma_f32_16x16x32_f16(a0v, bfA[3][0], z4, 0, 0, 0); \
        f32x4 aB0 = __builtin_amdgcn_mfma_f32_16x16x32_f16(a0v, bfB[0][0], z4, 0, 0, 0); \
        f32x4 aB1 = __builtin_amdgcn_mfma_f32_16x16x32_f16(a0v, bfB[1][0], z4, 0, 0, 0); \
        f32x4 aB2 = __builtin_amdgcn_mfma_f32_16x16x32_f16(a0v, bfB[2][0], z4, 0, 0, 0); \
        f32x4 aB3 = __builtin_amdgcn_mfma_f32_16x16x32_f16(a0v, bfB[3][0], z4, 0, 0, 0); \
        aA0 = __builtin_amdgcn_mfma_f32_16x16x32_f16(a1v, bfA[0][1], aA0, 0, 0, 0); \
        aA1 = __builtin_amdgcn_mfma_f32_16x16x32_f16(a1v, bfA[1][1], aA1, 0, 0, 0); \
        aA2 = __builtin_amdgcn_mfma_f32_16x16x32_f16(a1v, bfA[2][1], aA2, 0, 0, 0); \
        aA3 = __builtin_amdgcn_mfma_f32_16x16x32_f16(a1v, bfA[3][1], aA3, 0, 0, 0); \
        aB0 = __builtin_amdgcn_mfma_f32_16x16x32_f16(a1v, bfB[0][1], aB0, 0, 0, 0); \
        aB1 = __builtin_amdgcn_mfma_f32_16x16x32_f16(a1v, bfB[1][1], aB1, 0, 0, 0); \
        aB2 = __builtin_amdgcn_mfma_f32_16x16x32_f16(a1v, bfB[2][1], aB2, 0, 0, 0); \
        aB3 = __builtin_amdgcn_mfma_f32_16x16x32_f16(a1v, bfB[3][1], aB3, 0, 0, 0); \
        aA0 = __builtin_amdgcn_mfma_f32_16x16x32_f16(a2v, bfA[0][2], aA0, 0, 0, 0); \
        aA1 = __builtin_amdgcn_mfma_f32_16x16x32_f16(a2v, bfA[1][2], aA1, 0, 0, 0); \
        aA2 = __builtin_amdgcn_mfma_f32_16x16x32_f16(a2v, bfA[2][2], aA2, 0, 0, 0); \
        aA3 = __builtin_amdgcn_mfma_f32_16x16x32_f16(a2v, bfA[3][2], aA3, 0, 0, 0); \
        aB0 = __builtin_amdgcn_mfma_f32_16x16x32_f16(a2v, bfB[0][2], aB0, 0, 0, 0); \
        aB1 = __builtin_amdgcn_mfma_f32_16x16x32_f16(a2v, bfB[1][2], aB1, 0, 0, 0); \
        aB2 = __builtin_amdgcn_mfma_f32_16x16x32_f16(a2v, bfB[2][2], aB2, 0, 0, 0); \
        aB3 = __builtin_amdgcn_mfma_f32_16x16x32_f16(a2v, bfB[3][2], aB3, 0, 0, 0); \
        aA0 = __builtin_amdgcn_mfma_f32_16x16x32_f16(a3v, bfA[0][3], aA0, 0, 0, 0); \
        aA1 = __builtin_amdgcn_mfma_f32_16x16x32_f16(a3v, bfA[1][3], aA1, 0, 0, 0); \
        aA2 = __builtin_amdgcn_mfma_f32_16x16x32_f16(a3v, bfA[2][3], aA2, 0, 0, 0); \
        aA3 = __builtin_amdgcn_mfma_f32_16x16x32_f16(a3v, bfA[3][3], aA3, 0, 0, 0); \
        aB0 = __builtin_amdgcn_mfma_f32_16x16x32_f16(a3v, bfB[0][3], aB0, 0, 0, 0); \
        aB1 = __builtin_amdgcn_mfma_f32_16x16x32_f16(a3v, bfB[1][3], aB1, 0, 0, 0); \
        aB2 = __builtin_amdgcn_mfma_f32_16x16x32_f16(a3v, bfB[2][3], aB2, 0, 0, 0); \
        aB3 = __builtin_amdgcn_mfma_f32_16x16x32_f16(a3v, bfB[3][3], aB3, 0, 0, 0); \
        if (act) {                                                             \
            float gi = (grpB ? aB0[0] : aA0[0]) + G.x;                         \
            float gf = (grpB ? aB1[0] : aA1[0]) + G.y;                         \
            float gg = (grpB ? aB2[0] : aA2[0]) + G.z;                         \
            float go = (grpB ? aB3[0] : aA3[0]) + G.w;                         \
            if (PF) { G = *gq; gq += HH; }    /* reissue prefetch (t+4) */     \
            c_state = fast_sigmoid(gf) * c_state + fast_sigmoid(gi) * fast_tanh(gg); \
            float h = fast_sigmoid(go) * fast_tanh(c_state);                   \
            hsf[pb ^ 1][unit] = (__half)h;                                     \
            *outp = h;                                                         \
            outp += ostep;                                                     \
        }                                                                      \
        rec_barrier();                                                         \
        pb ^= 1;                                                               \
    } while (0)

    for (int it = 0; it < 99; ++it) {          // steps 0..395, prefetch valid
        REC_STEP(g0, 1);
        REC_STEP(g1, 1);
        REC_STEP(g2, 1);
        REC_STEP(g3, 1);
    }
    // epilogue: steps 396..399, no prefetch
    REC_STEP(g0, 0);
    REC_STEP(g1, 0);
    REC_STEP(g2, 0);
    REC_STEP(g3, 0);
#undef REC_STEP
}

// ---------------- K4: fused cum (blocks 0..1) + MFMA mlp (blocks 2..52) ----
// cum and mlp both depend only on rnn; k_scores consumes both outputs.
// Fusing saves a launch gap and hides cum's ~12 µs under mlp (r9: −18 µs).
#define PXBLKS 26
#define HDBLKS 25
#define AP 272          // k_mlp A-tile row stride in shorts
#define UCP 116         // uc tile row stride in floats
__global__ __launch_bounds__(256, 2)
void k_cum_mlp(const float* __restrict__ rnn, float* __restrict__ cum,
               const float* __restrict__ a1p,
               const float* __restrict__ ac1p, const float* __restrict__ ab1p,
               const short* __restrict__ wfD, const short* __restrict__ wfE,
               const short* __restrict__ wfHC, const short* __restrict__ wfHB,
               const float* __restrict__ bc1p, const float* __restrict__ bb1p,
               const float* __restrict__ ac2p, const float* __restrict__ ab2p,
               const float* __restrict__ Wc2, const float* __restrict__ bc2,
               const float* __restrict__ Wb2, const float* __restrict__ bb2,
               float* __restrict__ pxd, float* __restrict__ pxe,
               float* __restrict__ cls_out, float* __restrict__ bin_out) {
    int tid = threadIdx.x;
    if (blockIdx.x < BB) {
        // ---- cumsum over time: single fused sequential scan
        int b = blockIdx.x;
        int f = tid;                // 256 threads
        float run = 0.f;
        cum[(size_t)(b * NN) * FF + f] = 0.f;      // xp row 0 = zeros
        const float* rp = rnn + (size_t)b * SS * FF + f;
        float* cp = cum + ((size_t)b * NN + 1) * FF + f;
#pragma unroll 8
        for (int t = 0; t < SS; ++t) {
            run += rp[(size_t)t * FF];
            cp[(size_t)t * FF] = run;
        }
        return;
    }
    int blk = blockIdx.x - BB;
    bool is_px = (blk < PXBLKS);
    int rowbase = is_px ? blk * 32 : (blk - PXBLKS) * 32;
    int nrows_tot = is_px ? BB * NN : BB * SS;

    __shared__ __align__(16) short dth[2][32][AP];
    __shared__ float ucsh[2][32][UCP];

    // ---- build A tiles (rows = data rows)
    {
        int row = tid >> 3;
        int fb = (tid & 7) * 32;
        int rg = rowbase + row;
        float src[32];
        if (is_px) {
            float a1 = a1p[0];
            int b = rg / NN, n = rg % NN;
            bool valid = (rg < nrows_tot) && (n > 0);
            const float* sp = valid ? (rnn + (b * SS + n - 1) * FF + fb) : nullptr;
#pragma unroll
            for (int c4 = 0; c4 < 8; ++c4) {
                float4 v = valid ? *(const float4*)(sp + c4 * 4) : make_float4(0,0,0,0);
                src[c4*4] = v.x; src[c4*4+1] = v.y; src[c4*4+2] = v.z; src[c4*4+3] = v.w;
            }
            union { short8 s; unsigned short u[8]; } h8;
#pragma unroll
            for (int c8 = 0; c8 < 4; ++c8) {
#pragma unroll
                for (int e = 0; e < 8; ++e) h8.u[e] = f2bf(prelu_f(src[c8*8+e], a1));
                *(short8*)(&dth[0][row][fb + c8 * 8]) = h8.s;
            }
        } else {
            float ac1 = ac1p[0], ab1 = ab1p[0];
            bool valid = (rg < nrows_tot);
            const float* sp = valid ? (rnn + rg * FF + fb) : nullptr;
#pragma unroll
            for (int c4 = 0; c4 < 8; ++c4) {
                float4 v = valid ? *(const float4*)(sp + c4 * 4) : make_float4(0,0,0,0);
                src[c4*4] = v.x; src[c4*4+1] = v.y; src[c4*4+2] = v.z; src[c4*4+3] = v.w;
            }
            union { short8 s; unsigned short u[8]; } hc, hb;
#pragma unroll
            for (int c8 = 0; c8 < 4; ++c8) {
#pragma unroll
                for (int e = 0; e < 8; ++e) {
                    hc.u[e] = f2bf(prelu_f(src[c8*8+e], ac1));
                    hb.u[e] = f2bf(prelu_f(src[c8*8+e], ab1));
                }
                *(short8*)(&dth[0][row][fb + c8 * 8]) = hc.s;
                *(short8*)(&dth[1][row][fb + c8 * 8]) = hb.s;
            }
        }
    }
    __syncthreads();

    int lane = tid & 63;
    int wv = tid >> 6;
    int quad = lane >> 4;
    int l15 = lane & 15;
    int kt0 = wv * 2, kt1 = wv * 2 + 1;
    bool has1 = (kt1 < 7);

    const short8* wp0 = (const short8*)(is_px ? wfD : wfHC);
    const short8* wp1 = (const short8*)(is_px ? wfE : wfHB);

    // acc[path][mt][kt]
    f32x4 acc[2][2][2];
#pragma unroll
    for (int p = 0; p < 2; ++p)
#pragma unroll
        for (int mt = 0; mt < 2; ++mt)
#pragma unroll
            for (int kk = 0; kk < 2; ++kk) acc[p][mt][kk] = (f32x4){0.f,0.f,0.f,0.f};

#pragma unroll
    for (int ks = 0; ks < 8; ++ks) {
        short8 b00 = wp0[((kt0 * 8 + ks) * 4 + quad) * 16 + l15];
        short8 b01 = has1 ? wp0[((kt1 * 8 + ks) * 4 + quad) * 16 + l15] : b00;
        short8 b10 = wp1[((kt0 * 8 + ks) * 4 + quad) * 16 + l15];
        short8 b11 = has1 ? wp1[((kt1 * 8 + ks) * 4 + quad) * 16 + l15] : b10;
#pragma unroll
        for (int mt = 0; mt < 2; ++mt) {
            short8 a0 = *(const short8*)(&dth[0][mt * 16 + l15][ks * 32 + quad * 8]);
            short8 a1v = is_px ? a0
                       : *(const short8*)(&dth[1][mt * 16 + l15][ks * 32 + quad * 8]);
            acc[0][mt][0] = __builtin_amdgcn_mfma_f32_16x16x32_bf16(a0, b00, acc[0][mt][0], 0, 0, 0);
            acc[1][mt][0] = __builtin_amdgcn_mfma_f32_16x16x32_bf16(a1v, b10, acc[1][mt][0], 0, 0, 0);
            if (has1) {
                acc[0][mt][1] = __builtin_amdgcn_mfma_f32_16x16x32_bf16(a0, b01, acc[0][mt][1], 0, 0, 0);
                acc[1][mt][1] = __builtin_amdgcn_mfma_f32_16x16x32_bf16(a1v, b11, acc[1][mt][1], 0, 0, 0);
            }
        }
    }

    int kout0 = kt0 * 16 + l15;
    int kout1 = has1 ? (kt1 * 16 + l15) : 0;

    if (is_px) {
#pragma unroll
        for (int mt = 0; mt < 2; ++mt) {
#pragma unroll
            for (int r = 0; r < 4; ++r) {
                int m = mt * 16 + quad * 4 + r;
                int rg = rowbase + m;
                if (rg < nrows_tot) {
                    pxd[rg * KP + kout0] = acc[0][mt][0][r];
                    pxe[rg * KP + kout0] = acc[1][mt][0][r];
                    if (has1) {
                        pxd[rg * KP + kout1] = acc[0][mt][1][r];
                        pxe[rg * KP + kout1] = acc[1][mt][1][r];
                    }
                }
            }
        }
        return;
    }

    // heads: layer1 activation -> LDS, then layer2 matvecs
    float bc0 = bc1p[kout0], bc1v = bc1p[kout1];
    float bb0 = bb1p[kout0], bb1v = bb1p[kout1];
    float ac2 = ac2p[0], ab2 = ab2p[0];
#pragma unroll
    for (int mt = 0; mt < 2; ++mt) {
#pragma unroll
        for (int r = 0; r < 4; ++r) {
            int m = mt * 16 + quad * 4 + r;
            ucsh[0][m][kout0] = prelu_f(acc[0][mt][0][r] + bc0, ac2);
            ucsh[1][m][kout0] = prelu_f(acc[1][mt][0][r] + bb0, ab2);
            if (has1) {
                ucsh[0][m][kout1] = prelu_f(acc[0][mt][1][r] + bc1v, ac2);
                ucsh[1][m][kout1] = prelu_f(acc[1][mt][1][r] + bb1v, ab2);
            }
        }
    }
    __syncthreads();
    {
        int row = tid >> 3;
        int oc = tid & 7;
        int rg = rowbase + row;
        bool valid = (rg < nrows_tot);
        for (int o = oc; o < NCLS; o += 8) {
            float s = bc2[o];
            const float* w = Wc2 + o * KH;
#pragma unroll 4
            for (int k = 0; k < KH; ++k) s += w[k] * ucsh[0][row][k];
            if (valid) cls_out[rg * NCLS + o] = s;
        }
        // bin: 32 rows x 2 outputs = 64 work items
        if (tid < 64) {
            int row2 = tid >> 1, o = tid & 1;
            int rg2 = rowbase + row2;
            float s = bb2[o];
            const float* w = Wb2 + o * KH;
#pragma unroll 4
            for (int k = 0; k < KH; ++k) s += w[k] * ucsh[1][row2][k];
            if (rg2 < nrows_tot) bin_out[rg2 * 2 + o] = s;
        }
    }
}

// ---------------- K5: scores — conflict-fixed LDS layouts ------------------
#define JT 32
#define JTILES 13
#define NP2 201
#define APS 280         // k_scores A-tile row stride in shorts
#define CIP 264         // padded cish row: FF + FF/32
__global__ __launch_bounds__(256, 3)
void k_scores(const float* __restrict__ cum,
              const short* __restrict__ wfrag,
              const float* __restrict__ pxd, const float* __restrict__ pxe,
              const float* __restrict__ b1p, const float* __restrict__ w2p,
              const float* __restrict__ b2p,
              const float* __restrict__ a1p, const float* __restrict__ a2p,
              float* __restrict__ scores, float* __restrict__ dpcol) {
    int blk = blockIdx.x;
    int jt = blk % JTILES;
    int ipair = (blk / JTILES) % NP2;
    int b = blk / (JTILES * NP2);
    int tid = threadIdx.x;
    float a1 = a1p[0], a2 = a2p[0];
    int jbase = jt * JT;
    int i0 = ipair * 2;
    int i1 = i0 + 1;
    bool has_i1 = (i1 <= SS);
    int i1c = has_i1 ? i1 : i0;

    __shared__ __align__(16) float cish[2][CIP];
    __shared__ __align__(16) short dth[2][JT][APS];
    __shared__ float red[2][4][JT];

    cish[0][tid + (tid >> 5)] = cum[(b * NN + i0) * FF + tid];
    cish[1][tid + (tid >> 5)] = cum[(b * NN + i1c) * FF + tid];
    __syncthreads();

    {
        int row = tid >> 3;
        int fb = (tid & 7) * 32;
        int fbq = fb + (tid & 7);       // padded cish base for this chunk
        int jg = jbase + row;
        int jc = (jg <= SS) ? jg : SS;
        const float* cj = cum + (b * NN + jc) * FF + fb;
        float4 v[8];
#pragma unroll
        for (int c8 = 0; c8 < 4; ++c8) {
            v[2 * c8] = *(const float4*)(cj + c8 * 8);
            v[2 * c8 + 1] = *(const float4*)(cj + c8 * 8 + 4);
        }
#pragma unroll
        for (int ii = 0; ii < 2; ++ii) {
            const float* cio = &cish[ii][0];
#pragma unroll
            for (int c8 = 0; c8 < 4; ++c8) {
                float dv[8] = { v[2*c8].x, v[2*c8].y, v[2*c8].z, v[2*c8].w,
                                v[2*c8+1].x, v[2*c8+1].y, v[2*c8+1].z, v[2*c8+1].w };
                union { short8 s; unsigned short u[8]; } h8;
#pragma unroll
                for (int e = 0; e < 8; ++e) {
                    float d = prelu_f(dv[e] - cio[fbq + c8 * 8 + e], a1);
                    h8.u[e] = f2bf(d);
                }
                *(short8*)(&dth[ii][row][fb + c8 * 8]) = h8.s;
            }
        }
    }
    __syncthreads();

    int lane = tid & 63;
    int wv = tid >> 6;
    int quad = lane >> 4;
    int l15 = lane & 15;
    int kt0 = wv * 2, kt1 = wv * 2 + 1;
    bool has1 = (kt1 < 7);

    const short8* wf = (const short8*)wfrag;
    f32x4 acc[2][2][2];
#pragma unroll
    for (int ii = 0; ii < 2; ++ii)
#pragma unroll
        for (int mt = 0; mt < 2; ++mt)
#pragma unroll
            for (int kk = 0; kk < 2; ++kk) acc[ii][mt][kk] = (f32x4){0.f,0.f,0.f,0.f};

#pragma unroll
    for (int ks = 0; ks < 8; ++ks) {
        short8 b0 = wf[((kt0 * 8 + ks) * 4 + quad) * 16 + l15];
        short8 b1v = has1 ? wf[((kt1 * 8 + ks) * 4 + quad) * 16 + l15] : b0;
#pragma unroll
        for (int ii = 0; ii < 2; ++ii) {
#pragma unroll
            for (int mt = 0; mt < 2; ++mt) {
                short8 a = *(const short8*)(&dth[ii][mt * 16 + l15][ks * 32 + quad * 8]);
                acc[ii][mt][0] = __builtin_amdgcn_mfma_f32_16x16x32_bf16(a, b0, acc[ii][mt][0], 0, 0, 0);
                if (has1)
                    acc[ii][mt][1] = __builtin_amdgcn_mfma_f32_16x16x32_bf16(a, b1v, acc[ii][mt][1], 0, 0, 0);
            }
        }
    }

    int kout0 = kt0 * 16 + l15;
    int kout1 = has1 ? (kt1 * 16 + l15) : 0;
    float bb0 = b1p[kout0], bb1v = b1p[kout1];
    float w20 = w2p[kout0];
    float w21 = has1 ? w2p[kout1] : 0.f;

#pragma unroll
    for (int ii = 0; ii < 2; ++ii) {
        int iv = ii ? i1c : i0;
        float pd0 = pxd[(b * NN + iv) * KP + kout0];
        float pd1 = pxd[(b * NN + iv) * KP + kout1];
#pragma unroll
        for (int mt = 0; mt < 2; ++mt) {
#pragma unroll
            for (int r = 0; r < 4; ++r) {
                int m = mt * 16 + quad * 4 + r;
                int jg = jbase + m;
                int jc = (jg <= SS) ? jg : SS;
                float pe0 = pxe[(b * NN + jc) * KP + kout0];
                float pe1 = pxe[(b * NN + jc) * KP + kout1];
                float h0 = acc[ii][mt][0][r] + pd0 + pe0 + bb0;
                float s = w20 * prelu_f(h0, a2);
                float h1 = acc[ii][mt][1][r] + pd1 + pe1 + bb1v;
                s += w21 * prelu_f(h1, a2);
                s += __shfl_xor(s, 1);
                s += __shfl_xor(s, 2);
                s += __shfl_xor(s, 4);
                s += __shfl_xor(s, 8);
                if (l15 == 0) red[ii][wv][m] = s;
            }
        }
    }
    __syncthreads();
    if (tid < 2 * JT) {
        int ii = tid >> 5;
        int jl = tid & 31;
        int jg = jbase + jl;
        int iv = ii ? i1 : i0;
        if (jg <= SS && (ii == 0 || has_i1)) {
            float tot = red[ii][0][jl] + red[ii][1][jl] + red[ii][2][jl] + red[ii][3][jl] + b2p[0];
            scores[(b * NN + iv) * NN + jg] = tot;
            int d = jg - iv;
            if (d >= 1 && d <= MAXSEG) {
                // rotating-slot layout: slot = iv mod 64 (window<64 => injective)
                dpcol[(b * NN + jg) * 64 + (iv & 63)] = tot;
            }
        }
    }
}

// ---------------- K7: DP v3 — max-only DPP + ballot argmax -----------------
__global__ void k_dp(const float* __restrict__ dpcol, const int* __restrict__ lengths,
                     float* __restrict__ predF, float* __restrict__ prevF) {
    int b = blockIdx.x;
    int lane = threadIdx.x;          // 64 threads = 1 wave
    int len = lengths[b];
    if (lane == 0) prevF[b * NN] = 0.f;

    float blr = 0.f;                 // lane l holds best[k] for latest k ≡ l (mod 64)
    float predv = 0.f;

#define LO(I) (((I) > MAXSEG) ? ((I) - MAXSEG) : 0)
#define LOADCOL(ii) \
    ( ((ii) <= SS && (((lane - LO(ii)) & 63) < ((ii) - LO(ii)))) \
        ? dpcol[(b * NN + (ii)) * 64 + lane] : 0.f )

    float u0 = LOADCOL(1), u1 = LOADCOL(2), u2 = LOADCOL(3), u3 = LOADCOL(4);
    float u4 = LOADCOL(5), u5 = LOADCOL(6), u6 = LOADCOL(7), u7 = LOADCOL(8);

#define DPP_MAX(CTRL, v) do {                                                 \
        int _t = __builtin_amdgcn_update_dpp(__float_as_int(v),               \
                     __float_as_int(v), (CTRL), 0xF, 0xF, false);             \
        (v) = fmaxf((v), __int_as_float(_t));                                 \
    } while (0)

#define DP_STEP(I, BUF) do {                                                  \
        int lo_ = LO(I);                                                      \
        int cnt_ = (I) - lo_;                                                 \
        int off_ = (lane - lo_) & 63;                                         \
        float v0_ = (off_ < cnt_) ? blr + BUF : -INFINITY;                    \
        float v_ = v0_;                                                       \
        DPP_MAX(0x111, v_);   /* row_shr:1  */                                \
        DPP_MAX(0x112, v_);   /* row_shr:2  */                                \
        DPP_MAX(0x114, v_);   /* row_shr:4  */                                \
        DPP_MAX(0x118, v_);   /* row_shr:8  */                                \
        DPP_MAX(0x142, v_);   /* row_bcast:15 */                              \
        DPP_MAX(0x143, v_);   /* row_bcast:31 */                              \
        float m_ = __int_as_float(                                            \
            __builtin_amdgcn_readlane(__float_as_int(v_), 63));               \
        unsigned long long mk_ = __ballot(v0_ == m_);                         \
        int rot_ = lo_ & 63;                                                  \
        unsigned long long mr_ = rot_ ? ((mk_ >> rot_) | (mk_ << (64 - rot_))) \
                                      : mk_;                                  \
        int kb_ = lo_ + (__ffsll(mr_) - 1);                                   \
        if (lane == 0) {                                                      \
            prevF[b * NN + (I)] = (float)kb_;                                 \
            if ((I) == len) predv = m_;                                       \
        }                                                                     \
        if (lane == ((I) & 63)) blr = m_;                                     \
    } while (0)

    for (int i = 1; i <= SS; i += 8) {
        DP_STEP(i, u0);     u0 = LOADCOL(i + 8);
        DP_STEP(i + 1, u1); u1 = LOADCOL(i + 9);
        DP_STEP(i + 2, u2); u2 = LOADCOL(i + 10);
        DP_STEP(i + 3, u3); u3 = LOADCOL(i + 11);
        DP_STEP(i + 4, u4); u4 = LOADCOL(i + 12);
        DP_STEP(i + 5, u5); u5 = LOADCOL(i + 13);
        DP_STEP(i + 6, u6); u6 = LOADCOL(i + 14);
        DP_STEP(i + 7, u7); u7 = LOADCOL(i + 15);
    }
#undef DP_STEP
#undef DPP_MAX
#undef LOADCOL
#undef LO
    if (lane == 0) predF[b] = predv;
}

// ---------------- launch ---------------------------------------------------
extern "C" void kernel_launch(void* const* d_in, const int* in_sizes, int n_in,
                              void* d_out, int out_size, void* d_ws, size_t ws_size,
                              hipStream_t stream) {
    const float* x    = (const float*)d_in[0];
    const int* lengths= (const int*)d_in[1];
    const float* Wi_f = (const float*)d_in[2];
    const float* Wh_f = (const float*)d_in[3];
    const float* b_f  = (const float*)d_in[4];
    const float* Wi_b = (const float*)d_in[5];
    const float* Wh_b = (const float*)d_in[6];
    const float* b_b  = (const float*)d_in[7];
    const float* a1   = (const float*)d_in[8];
    const float* W1   = (const float*)d_in[9];
    const float* b1   = (const float*)d_in[10];
    const float* a2   = (const float*)d_in[11];
    const float* W2   = (const float*)d_in[12];
    const float* b2   = (const float*)d_in[13];
    const float* ac1  = (const float*)d_in[14];
    const float* Wc1  = (const float*)d_in[15];
    const float* bc1  = (const float*)d_in[16];
    const float* ac2  = (const float*)d_in[17];
    const float* Wc2  = (const float*)d_in[18];
    const float* bc2  = (const float*)d_in[19];
    const float* ab1  = (const float*)d_in[20];
    const float* Wb1  = (const float*)d_in[21];
    const float* bb1  = (const float*)d_in[22];
    const float* ab2  = (const float*)d_in[23];
    const float* Wb2  = (const float*)d_in[24];
    const float* bb2  = (const float*)d_in[25];

    float* out = (float*)d_out;
    float* scores = out + SCORES_OFF;
    float* cls    = out + CLS_OFF;
    float* bin    = out + BIN_OFF;
    float* pred   = out + PRED_OFF;
    float* prev   = out + PREV_OFF;

    float* ws    = (float*)d_ws;
    float* gx    = ws + WS_GX;
    float* dpcol = ws + WS_GX;       // reuse: gx dead after k_lstm_rec
    float* rnn   = ws + WS_RNN;
    float* cum   = ws + WS_CUM;
    float* pxd   = ws + WS_PXD;
    float* pxe   = ws + WS_PXE;
    float* w2p   = ws + WS_W2P;
    float* b1p   = ws + WS_B1P;
    __half* whp  = (__half*)(ws + WS_WHP);
    short* wfC   = (short*)(ws + WS_WFRAGC);
    short* wfD   = (short*)(ws + WS_WFRAGD);
    short* wfE   = (short*)(ws + WS_WFRAGE);
    short* wfHC  = (short*)(ws + WS_WFRAGHC);
    short* wfHB  = (short*)(ws + WS_WFRAGHB);
    float* bc1p  = ws + WS_BC1P;
    float* bb1p  = ws + WS_BB1P;

    k_lstm_pre<<<PREPBLKS + 4 * SS, 256, 0, stream>>>(x, Wi_f, b_f, Wi_b, b_b, gx,
                                                      W1, W2, b1, Wh_f, Wh_b,
                                                      Wc1, Wb1, bc1, bb1,
                                                      wfC, wfD, wfE, wfHC, wfHB,
                                                      w2p, b1p, bc1p, bb1p, whp);
    k_lstm_rec<<<4, 256, 0, stream>>>((const _Float16*)whp, gx, rnn);
    k_cum_mlp<<<BB + PXBLKS + HDBLKS, 256, 0, stream>>>(rnn, cum, a1, ac1, ab1,
                                                        wfD, wfE, wfHC, wfHB,
                                                        bc1p, bb1p, ac2, ab2,
                                                        Wc2, bc2, Wb2, bb2,
                                                        pxd, pxe, cls, bin);
    k_scores<<<BB * NP2 * JTILES, 256, 0, stream>>>(cum, wfC, pxd, pxe, b1p, w2p, b2,
                                                    a1, a2, scores, dpcol);
    k_dp<<<BB, 64, 0, stream>>>(dpcol, lengths, pred, prev);
}

// Round 11
// 527.871 us; speedup vs baseline: 1.0991x; 1.0493x over previous
//
#include <hip/hip_runtime.h>
#include <hip/hip_fp16.h>
#include <math.h>

// Problem constants
#define BB 2
#define SS 400
#define II 80
#define HH 128
#define FF 256          // 2*H
#define NN 401          // S+1
#define G4 512          // 4*H
#define MAXSEG 50
#define NCLS 50
#define KH 100          // rows of W1 / Wc1 / Wb1
#define KP 112          // KH padded to 7*16 for MFMA
#define FRAGF 14336     // floats per frag-packed W (28672 shorts)

// d_out layout (floats): scores | cls | bin | pred | prev
#define SCORES_OFF 0
#define CLS_OFF    (BB*NN*NN)
#define BIN_OFF    (CLS_OFF + BB*SS*NCLS)
#define PRED_OFF   (BIN_OFF + BB*SS*2)
#define PREV_OFF   (PRED_OFF + BB)

// workspace layout (float slots)
#define WS_GX      0                          // 819200; dead after rec -> dpcol (51328)
#define WS_RNN     (WS_GX + 4*SS*G4)          // B*S*F
#define WS_CUM     (WS_RNN + BB*SS*FF)        // B*N*F
#define WS_PXD     (WS_CUM + BB*NN*FF)        // B*N*KP
#define WS_PXE     (WS_PXD + BB*NN*KP)
#define WS_PART    (WS_PXE + BB*NN*KP)        // B*16*F (unused since cum fusion)
#define WS_W2P     (WS_PART + BB*16*FF)       // KP
#define WS_B1P     (WS_W2P + KP)              // KP
#define WS_WHP     (WS_B1P + KP)              // Wh f16 MFMA frags: 131072 halfs
#define WS_WFRAGC  (WS_WHP + 65536)
#define WS_WFRAGD  (WS_WFRAGC + FRAGF)
#define WS_WFRAGE  (WS_WFRAGD + FRAGF)
#define WS_WFRAGHC (WS_WFRAGE + FRAGF)
#define WS_WFRAGHB (WS_WFRAGHC + FRAGF)
#define WS_BC1P    (WS_WFRAGHB + FRAGF)       // KP
#define WS_BB1P    (WS_BC1P + KP)             // KP

typedef __attribute__((ext_vector_type(8))) short short8;
typedef __attribute__((ext_vector_type(4))) float f32x4;
typedef _Float16 f16x2 __attribute__((ext_vector_type(2)));
typedef _Float16 f16x8 __attribute__((ext_vector_type(8)));

__device__ __forceinline__ float prelu_f(float x, float a) {
    return x >= 0.f ? x : a * x;
}
__device__ __forceinline__ unsigned short f2bf(float x) {
    union { float f; unsigned u; } v; v.f = x;
    unsigned r = v.u + 0x7fffu + ((v.u >> 16) & 1u);   // RNE
    return (unsigned short)(r >> 16);
}
__device__ __forceinline__ float fast_sigmoid(float x) {
    return 1.f / (1.f + __expf(-x));
}
__device__ __forceinline__ float fast_tanh(float x) {
    return 1.f - 2.f / (1.f + __expf(2.f * x));
}
// m201-style barrier: LDS drained, but vmcnt (global loads/stores) stays
// in flight across the barrier — no "memory" clobber, no vmcnt drain.
__device__ __forceinline__ void rec_barrier() {
    __builtin_amdgcn_sched_barrier(0);
    asm volatile("s_waitcnt lgkmcnt(0)");
    __builtin_amdgcn_s_barrier();
    __builtin_amdgcn_sched_barrier(0);
}
__device__ __forceinline__ int fragidx(int k, int f) {
    int kt = k >> 4, l15 = k & 15;
    int ks = f >> 5, quad = (f >> 3) & 3, e = f & 7;
    return ((((kt * 8 + ks) * 4 + quad) * 16) + l15) * 8 + e;
}

// ---------------- K1: prep — whp pack (blk<512) + gx (Wi-reuse tiles) ------
// gx restructured: block = (chain, 8-step chunk) => 200 blocks (was 1600).
// x chunk staged in LDS (uniform broadcast reads), Wi k-chunks in regs,
// 8 accumulators/gate. Wi L2 traffic 262 MB -> 33 MB. Same f32 math,
// same 4-term accumulation grouping as the original.
#define GXTC 8
#define GXBLKS (4 * (SS / GXTC))      // 200
#define PREPBLKS (G4 + GXBLKS)
__global__ void k_lstm_pre(const float* __restrict__ x,
                           const float* __restrict__ Wi_f, const float* __restrict__ b_f,
                           const float* __restrict__ Wi_b, const float* __restrict__ b_b,
                           float* __restrict__ gx,
                           const float* __restrict__ Wh_f, const float* __restrict__ Wh_b,
                           __half* __restrict__ whp) {
    int blk0 = blockIdx.x;
    int tid = threadIdx.x;
    if (blk0 < G4) {
        // Pack Wh into fp16 MFMA B-fragments for mfma_f32_16x16x32_f16.
        int gq = blk0;                   // 0..511 = gate*128 + unit
        int gate = gq >> 7;
        int unit = gq & 127;
        int wv = unit >> 4, col = unit & 15;
        int dir = tid >> 7, k = tid & 127;
        int kt = k >> 5, lanehi = (k >> 3) & 3, e = k & 7;
        int lane = lanehi * 16 + col;
        const float* Wh = dir ? Wh_b : Wh_f;
        whp[(size_t)(((((dir * 4 + gate) * 8 + wv) * 4 + kt) * 64) + lane) * 8 + e] =
            (__half)Wh[gq * HH + k];
        return;
    }
    int gxb = blk0 - G4;               // 0..199
    int db = gxb / (SS / GXTC);
    int tc = gxb % (SS / GXTC);
    int b = db & 1, dir = db >> 1;
    const float* Wi = dir ? Wi_b : Wi_f;
    const float* bias = dir ? b_b : b_f;
    int t0 = tc * GXTC;

    __shared__ __align__(16) float xs[GXTC][II];
    for (int idx = tid; idx < GXTC * II; idx += 256) {
        int tt = idx / II, ii = idx - tt * II;
        int xt = dir ? (SS - 1 - (t0 + tt)) : (t0 + tt);
        xs[tt][ii] = x[(b * SS + xt) * II + ii];
    }
    __syncthreads();

    int g1 = tid + 256;
    const float* w0p = Wi + tid * II;
    const float* w1p = Wi + g1 * II;
    float acc0[GXTC], acc1[GXTC];
    {
        float b0v = bias[tid], b1v = bias[g1];
#pragma unroll
        for (int t = 0; t < GXTC; ++t) { acc0[t] = b0v; acc1[t] = b1v; }
    }
    for (int kc = 0; kc < 5; ++kc) {          // 5 chunks of 16 k
        float4 wa0 = *(const float4*)(w0p + kc * 16 + 0);
        float4 wa1 = *(const float4*)(w0p + kc * 16 + 4);
        float4 wa2 = *(const float4*)(w0p + kc * 16 + 8);
        float4 wa3 = *(const float4*)(w0p + kc * 16 + 12);
        float4 wb0 = *(const float4*)(w1p + kc * 16 + 0);
        float4 wb1 = *(const float4*)(w1p + kc * 16 + 4);
        float4 wb2 = *(const float4*)(w1p + kc * 16 + 8);
        float4 wb3 = *(const float4*)(w1p + kc * 16 + 12);
#pragma unroll
        for (int t = 0; t < GXTC; ++t) {
            float4 x0 = *(const float4*)(&xs[t][kc * 16 + 0]);
            float4 x1 = *(const float4*)(&xs[t][kc * 16 + 4]);
            float4 x2 = *(const float4*)(&xs[t][kc * 16 + 8]);
            float4 x3 = *(const float4*)(&xs[t][kc * 16 + 12]);
            acc0[t] += wa0.x * x0.x + wa0.y * x0.y + wa0.z * x0.z + wa0.w * x0.w;
            acc0[t] += wa1.x * x1.x + wa1.y * x1.y + wa1.z * x1.z + wa1.w * x1.w;
            acc0[t] += wa2.x * x2.x + wa2.y * x2.y + wa2.z * x2.z + wa2.w * x2.w;
            acc0[t] += wa3.x * x3.x + wa3.y * x3.y + wa3.z * x3.z + wa3.w * x3.w;
            acc1[t] += wb0.x * x0.x + wb0.y * x0.y + wb0.z * x0.z + wb0.w * x0.w;
            acc1[t] += wb1.x * x1.x + wb1.y * x1.y + wb1.z * x1.z + wb1.w * x1.w;
            acc1[t] += wb2.x * x2.x + wb2.y * x2.y + wb2.z * x2.z + wb2.w * x2.w;
            acc1[t] += wb3.x * x3.x + wb3.y * x3.y + wb3.z * x3.z + wb3.w * x3.w;
        }
    }
    // layout [db][t][unit][gate] so rec reads one float4 per lane
#pragma unroll
    for (int t = 0; t < GXTC; ++t) {
        gx[((size_t)(db * SS + t0 + t) * HH + (tid & 127)) * 4 + (tid >> 7)] = acc0[t];
        gx[((size_t)(db * SS + t0 + t) * HH + (g1 & 127)) * 4 + (g1 >> 7)] = acc1[t];
    }
}

// ---------------- K2: rec v7 (chains, blk<4) + W-frag packing (blk>=4) -----
// Packing blocks run on the 252 idle CUs during rec's ~225 µs (free).
// They write wfC/D/E/HC/HB + small vecs, consumed only by later kernels.
#define WPACKS (5 * KP)
__global__ __launch_bounds__(256, 1)
void k_lstm_rec(const _Float16* __restrict__ whf, const float* __restrict__ gxr,
                float* __restrict__ rnn_out,
                const float* __restrict__ W1, const float* __restrict__ W2,
                const float* __restrict__ b1,
                const float* __restrict__ Wc1, const float* __restrict__ Wb1,
                const float* __restrict__ bc1, const float* __restrict__ bb1,
                short* __restrict__ wfC, short* __restrict__ wfD,
                short* __restrict__ wfE, short* __restrict__ wfHC,
                short* __restrict__ wfHB,
                float* __restrict__ w2p, float* __restrict__ b1p,
                float* __restrict__ bc1p, float* __restrict__ bb1p) {
    int tid = threadIdx.x;
    if (blockIdx.x >= 4) {
        int blk0 = blockIdx.x - 4;       // 0..559
        int which = blk0 / KP;
        int k = blk0 % KP;
        float w = 0.f;
        short* dst = wfC;
        if (which == 0)      { if (k < KH) w = W1[k * (3 * FF) + tid];          dst = wfC; }
        else if (which == 1) { if (k < KH) w = W1[k * (3 * FF) + FF + tid];     dst = wfD; }
        else if (which == 2) { if (k < KH) w = W1[k * (3 * FF) + 2 * FF + tid]; dst = wfE; }
        else if (which == 3) { if (k < KH) w = Wc1[k * FF + tid];               dst = wfHC; }
        else                 { if (k < KH) w = Wb1[k * FF + tid];               dst = wfHB; }
        dst[fragidx(k, tid)] = (short)f2bf(w);
        if (tid == 0) {
            if (which == 0) {
                w2p[k] = (k < KH) ? W2[k] : 0.f;
                b1p[k] = (k < KH) ? b1[k] : 0.f;
            } else if (which == 3) {
                bc1p[k] = (k < KH) ? bc1[k] : 0.f;
            } else if (which == 4) {
                bb1p[k] = (k < KH) ? bb1[k] : 0.f;
            }
        }
        return;
    }
    int db = blockIdx.x;
    int b = db & 1, dir = db >> 1;
    int wv = tid >> 6;              // 0..3
    int lane = tid & 63;

    // B frags for the wave's two 16-unit groups (packed groups 2wv, 2wv+1)
    f16x8 bfA[4][4], bfB[4][4];
    {
        const f16x8* wp = (const f16x8*)whf;
#pragma unroll
        for (int g = 0; g < 4; ++g)
#pragma unroll
            for (int kt = 0; kt < 4; ++kt) {
                bfA[g][kt] = wp[((((dir * 4 + g) * 8 + (2 * wv)) * 4 + kt) * 64) + lane];
                bfB[g][kt] = wp[((((dir * 4 + g) * 8 + (2 * wv + 1)) * 4 + kt) * 64) + lane];
            }
    }

    __shared__ __align__(16) __half hsf[2][128];
    (&hsf[0][0])[tid] = (__half)0.f;           // 256 entries, 256 threads
    __syncthreads();

    bool act = (lane < 32);
    bool grpB = (lane >= 16);                  // within act: group select
    int unit = (wv << 5) + (lane & 31);        // valid for act lanes
    float c_state = 0.f;

    const float4* gp4 = (const float4*)gxr + (size_t)(db * SS) * HH + unit;
    float4 g0 = make_float4(0,0,0,0), g1 = g0, g2 = g0, g3 = g0;
    if (act) {
        g0 = gp4[0 * HH];
        g1 = gp4[1 * HH];
        g2 = gp4[2 * HH];
        g3 = gp4[3 * HH];
    }
    const float4* gq = gp4 + (size_t)4 * HH;   // marching prefetch cursor

    float* outp = rnn_out + ((size_t)b * SS + (dir ? (SS - 1) : 0)) * FF
                + dir * HH + unit;             // consumed only by act lanes
    const int ostep = dir ? -FF : FF;

    const f32x4 z4 = (f32x4){0.f, 0.f, 0.f, 0.f};
    int pb = 0;
    int hib = (lane >> 4) * 8;                 // k-chunk base within ktile
    bool aload = (lane & 3) == 0;              // A rows 0,4,8,12 hold h

    f16x8 a0v = (f16x8)(_Float16)0.f, a1v = a0v, a2v = a0v, a3v = a0v;

#define REC_STEP(G, PF) do {                                                   \
        if (aload) {                                                           \
            a0v = *(const f16x8*)(&hsf[pb][ 0 + hib]);                         \
            a1v = *(const f16x8*)(&hsf[pb][32 + hib]);                         \
            a2v = *(const f16x8*)(&hsf[pb][64 + hib]);                         \
            a3v = *(const f16x8*)(&hsf[pb][96 + hib]);                         \
        }                                                                      \
        f32x4 aA0 = __builtin_amdgcn_mfma_f32_16x16x32_f16(a0v, bfA[0][0], z4, 0, 0, 0); \
        f32x4 aA1 = __builtin_amdgcn_mfma_f32_16x16x32_f16(a0v, bfA[1][0], z4, 0, 0, 0); \
        f32x4 aA2 = __builtin_amdgcn_mfma_f32_16x16x32_f16(a0v, bfA[2][0], z4, 0, 0, 0); \
        f32x4 aA3 = __builtin_amdgcn_mfma_f32_16x16x32_f16(a0v, bfA[3][0], z4, 0, 0, 0); \
        f32x4 aB0 = __builtin_amdgcn_mfma_f32_16x16x32_f16(a0v, bfB[0][0], z4, 0, 0, 0); \
        f32x4 aB1 = __builtin_amdgcn_mfma_f32_16x16x32_f16(a0v, bfB[1][0], z4, 0, 0, 0); \
        f32x4 aB2 = __builtin_amdgcn_mfma_f32_16x16x32_f16(a0v, bfB[2][0], z4, 0, 0, 0); \
        f32x4 aB3 = __builtin_amdgcn_mfma_f32_16x16x32_f16(a0v, bfB[3][0], z4, 0, 0, 0); \
        aA0 = __builtin_amdgcn_mfma_f32_16x16x32_f16(a1v, bfA[0][1], aA0, 0, 0, 0); \
        aA1 = __builtin_amdgcn_mfma_f32_16x16x32_f16(a1v, bfA[1][1], aA1, 0, 0, 0); \
        aA2 = __builtin_amdgcn_mfma_f32_16x16x32_f16(a1v, bfA[2][1], aA2, 0, 0, 0); \
        aA3 = __builtin_amdgcn_mfma_f32_16x16x32_f16(a1v, bfA[3][1], aA3, 0, 0, 0); \
        aB0 = __builtin_amdgcn_mfma_f32_16x16x32_f16(a1v, bfB[0][1], aB0, 0, 0, 0); \
        aB1 = __builtin_amdgcn_mfma_f32_16x16x32_f16(a1v, bfB[1][1], aB1, 0, 0, 0); \
        aB2 = __builtin_amdgcn_mfma_f32_16x16x32_f16(a1v, bfB[2][1], aB2, 0, 0, 0); \
        aB3 = __builtin_amdgcn_mfma_f32_16x16x32_f16(a1v, bfB[3][1], aB3, 0, 0, 0); \
        aA0 = __builtin_amdgcn_mfma_f32_16x16x32_f16(a2v, bfA[0][2], aA0, 0, 0, 0); \
        aA1 = __builtin_amdgcn_mfma_f32_16x16x32_f16(a2v, bfA[1][2], aA1, 0, 0, 0); \
        aA2 = __builtin_amdgcn_mfma_f32_16x16x32_f16(a2v, bfA[2][2], aA2, 0, 0, 0); \
        aA3 = __builtin_amdgcn_mfma_f32_16x16x32_f16(a2v, bfA[3][2], aA3, 0, 0, 0); \
        aB0 = __builtin_amdgcn_mfma_f32_16x16x32_f16(a2v, bfB[0][2], aB0, 0, 0, 0); \
        aB1 = __builtin_amdgcn_mfma_f32_16x16x32_f16(a2v, bfB[1][2], aB1, 0, 0, 0); \
        aB2 = __builtin_amdgcn_mfma_f32_16x16x32_f16(a2v, bfB[2][2], aB2, 0, 0, 0); \
        aB3 = __builtin_amdgcn_mfma_f32_16x16x32_f16(a2v, bfB[3][2], aB3, 0, 0, 0); \
        aA0 = __builtin_amdgcn_mfma_f32_16x16x32_f16(a3v, bfA[0][3], aA0, 0, 0, 0); \
        aA1 = __builtin_amdgcn_mfma_f32_16x16x32_f16(a3v, bfA[1][3], aA1, 0, 0, 0); \
        aA2 = __builtin_amdgcn_mfma_f32_16x16x32_f16(a3v, bfA[2][3], aA2, 0, 0, 0); \
        aA3 = __builtin_amdgcn_mfma_f32_16x16x32_f16(a3v, bfA[3][3], aA3, 0, 0, 0); \
        aB0 = __builtin_amdgcn_mfma_f32_16x16x32_f16(a3v, bfB[0][3], aB0, 0, 0, 0); \
        aB1 = __builtin_amdgcn_mfma_f32_16x16x32_f16(a3v, bfB[1][3], aB1, 0, 0, 0); \
        aB2 = __builtin_amdgcn_mfma_f32_16x16x32_f16(a3v, bfB[2][3], aB2, 0, 0, 0); \
        aB3 = __builtin_amdgcn_mfma_f32_16x16x32_f16(a3v, bfB[3][3], aB3, 0, 0, 0); \
        if (act) {                                                             \
            float gi = (grpB ? aB0[0] : aA0[0]) + G.x;                         \
            float gf = (grpB ? aB1[0] : aA1[0]) + G.y;                         \
            float gg = (grpB ? aB2[0] : aA2[0]) + G.z;                         \
            float go = (grpB ? aB3[0] : aA3[0]) + G.w;                         \
            if (PF) { G = *gq; gq += HH; }    /* reissue prefetch (t+4) */     \
            c_state = fast_sigmoid(gf) * c_state + fast_sigmoid(gi) * fast_tanh(gg); \
            float h = fast_sigmoid(go) * fast_tanh(c_state);                   \
            hsf[pb ^ 1][unit] = (__half)h;                                     \
            *outp = h;                                                         \
            outp += ostep;                                                     \
        }                                                                      \
        rec_barrier();                                                         \
        pb ^= 1;                                                               \
    } while (0)

    for (int it = 0; it < 99; ++it) {          // steps 0..395, prefetch valid
        REC_STEP(g0, 1);
        REC_STEP(g1, 1);
        REC_STEP(g2, 1);
        REC_STEP(g3, 1);
    }
    // epilogue: steps 396..399, no prefetch
    REC_STEP(g0, 0);
    REC_STEP(g1, 0);
    REC_STEP(g2, 0);
    REC_STEP(g3, 0);
#undef REC_STEP
}

// ---------------- K4: fused cum (blocks 0..1) + MFMA mlp (blocks 2..52) ----
#define PXBLKS 26
#define HDBLKS 25
#define AP 272          // k_mlp A-tile row stride in shorts
#define UCP 116         // uc tile row stride in floats
__global__ __launch_bounds__(256, 2)
void k_cum_mlp(const float* __restrict__ rnn, float* __restrict__ cum,
               const float* __restrict__ a1p,
               const float* __restrict__ ac1p, const float* __restrict__ ab1p,
               const short* __restrict__ wfD, const short* __restrict__ wfE,
               const short* __restrict__ wfHC, const short* __restrict__ wfHB,
               const float* __restrict__ bc1p, const float* __restrict__ bb1p,
               const float* __restrict__ ac2p, const float* __restrict__ ab2p,
               const float* __restrict__ Wc2, const float* __restrict__ bc2,
               const float* __restrict__ Wb2, const float* __restrict__ bb2,
               float* __restrict__ pxd, float* __restrict__ pxe,
               float* __restrict__ cls_out, float* __restrict__ bin_out) {
    int tid = threadIdx.x;
    if (blockIdx.x < BB) {
        // ---- cumsum over time: single fused sequential scan
        int b = blockIdx.x;
        int f = tid;                // 256 threads
        float run = 0.f;
        cum[(size_t)(b * NN) * FF + f] = 0.f;      // xp row 0 = zeros
        const float* rp = rnn + (size_t)b * SS * FF + f;
        float* cp = cum + ((size_t)b * NN + 1) * FF + f;
#pragma unroll 8
        for (int t = 0; t < SS; ++t) {
            run += rp[(size_t)t * FF];
            cp[(size_t)t * FF] = run;
        }
        return;
    }
    int blk = blockIdx.x - BB;
    bool is_px = (blk < PXBLKS);
    int rowbase = is_px ? blk * 32 : (blk - PXBLKS) * 32;
    int nrows_tot = is_px ? BB * NN : BB * SS;

    __shared__ __align__(16) short dth[2][32][AP];
    __shared__ float ucsh[2][32][UCP];

    // ---- build A tiles (rows = data rows)
    {
        int row = tid >> 3;
        int fb = (tid & 7) * 32;
        int rg = rowbase + row;
        float src[32];
        if (is_px) {
            float a1 = a1p[0];
            int b = rg / NN, n = rg % NN;
            bool valid = (rg < nrows_tot) && (n > 0);
            const float* sp = valid ? (rnn + (b * SS + n - 1) * FF + fb) : nullptr;
#pragma unroll
            for (int c4 = 0; c4 < 8; ++c4) {
                float4 v = valid ? *(const float4*)(sp + c4 * 4) : make_float4(0,0,0,0);
                src[c4*4] = v.x; src[c4*4+1] = v.y; src[c4*4+2] = v.z; src[c4*4+3] = v.w;
            }
            union { short8 s; unsigned short u[8]; } h8;
#pragma unroll
            for (int c8 = 0; c8 < 4; ++c8) {
#pragma unroll
                for (int e = 0; e < 8; ++e) h8.u[e] = f2bf(prelu_f(src[c8*8+e], a1));
                *(short8*)(&dth[0][row][fb + c8 * 8]) = h8.s;
            }
        } else {
            float ac1 = ac1p[0], ab1 = ab1p[0];
            bool valid = (rg < nrows_tot);
            const float* sp = valid ? (rnn + rg * FF + fb) : nullptr;
#pragma unroll
            for (int c4 = 0; c4 < 8; ++c4) {
                float4 v = valid ? *(const float4*)(sp + c4 * 4) : make_float4(0,0,0,0);
                src[c4*4] = v.x; src[c4*4+1] = v.y; src[c4*4+2] = v.z; src[c4*4+3] = v.w;
            }
            union { short8 s; unsigned short u[8]; } hc, hb;
#pragma unroll
            for (int c8 = 0; c8 < 4; ++c8) {
#pragma unroll
                for (int e = 0; e < 8; ++e) {
                    hc.u[e] = f2bf(prelu_f(src[c8*8+e], ac1));
                    hb.u[e] = f2bf(prelu_f(src[c8*8+e], ab1));
                }
                *(short8*)(&dth[0][row][fb + c8 * 8]) = hc.s;
                *(short8*)(&dth[1][row][fb + c8 * 8]) = hb.s;
            }
        }
    }
    __syncthreads();

    int lane = tid & 63;
    int wv = tid >> 6;
    int quad = lane >> 4;
    int l15 = lane & 15;
    int kt0 = wv * 2, kt1 = wv * 2 + 1;
    bool has1 = (kt1 < 7);

    const short8* wp0 = (const short8*)(is_px ? wfD : wfHC);
    const short8* wp1 = (const short8*)(is_px ? wfE : wfHB);

    // acc[path][mt][kt]
    f32x4 acc[2][2][2];
#pragma unroll
    for (int p = 0; p < 2; ++p)
#pragma unroll
        for (int mt = 0; mt < 2; ++mt)
#pragma unroll
            for (int kk = 0; kk < 2; ++kk) acc[p][mt][kk] = (f32x4){0.f,0.f,0.f,0.f};

#pragma unroll
    for (int ks = 0; ks < 8; ++ks) {
        short8 b00 = wp0[((kt0 * 8 + ks) * 4 + quad) * 16 + l15];
        short8 b01 = has1 ? wp0[((kt1 * 8 + ks) * 4 + quad) * 16 + l15] : b00;
        short8 b10 = wp1[((kt0 * 8 + ks) * 4 + quad) * 16 + l15];
        short8 b11 = has1 ? wp1[((kt1 * 8 + ks) * 4 + quad) * 16 + l15] : b10;
#pragma unroll
        for (int mt = 0; mt < 2; ++mt) {
            short8 a0 = *(const short8*)(&dth[0][mt * 16 + l15][ks * 32 + quad * 8]);
            short8 a1v = is_px ? a0
                       : *(const short8*)(&dth[1][mt * 16 + l15][ks * 32 + quad * 8]);
            acc[0][mt][0] = __builtin_amdgcn_mfma_f32_16x16x32_bf16(a0, b00, acc[0][mt][0], 0, 0, 0);
            acc[1][mt][0] = __builtin_amdgcn_mfma_f32_16x16x32_bf16(a1v, b10, acc[1][mt][0], 0, 0, 0);
            if (has1) {
                acc[0][mt][1] = __builtin_amdgcn_mfma_f32_16x16x32_bf16(a0, b01, acc[0][mt][1], 0, 0, 0);
                acc[1][mt][1] = __builtin_amdgcn_mfma_f32_16x16x32_bf16(a1v, b11, acc[1][mt][1], 0, 0, 0);
            }
        }
    }

    int kout0 = kt0 * 16 + l15;
    int kout1 = has1 ? (kt1 * 16 + l15) : 0;

    if (is_px) {
#pragma unroll
        for (int mt = 0; mt < 2; ++mt) {
#pragma unroll
            for (int r = 0; r < 4; ++r) {
                int m = mt * 16 + quad * 4 + r;
                int rg = rowbase + m;
                if (rg < nrows_tot) {
                    pxd[rg * KP + kout0] = acc[0][mt][0][r];
                    pxe[rg * KP + kout0] = acc[1][mt][0][r];
                    if (has1) {
                        pxd[rg * KP + kout1] = acc[0][mt][1][r];
                        pxe[rg * KP + kout1] = acc[1][mt][1][r];
                    }
                }
            }
        }
        return;
    }

    // heads: layer1 activation -> LDS, then layer2 matvecs
    float bc0 = bc1p[kout0], bc1v = bc1p[kout1];
    float bb0 = bb1p[kout0], bb1v = bb1p[kout1];
    float ac2 = ac2p[0], ab2 = ab2p[0];
#pragma unroll
    for (int mt = 0; mt < 2; ++mt) {
#pragma unroll
        for (int r = 0; r < 4; ++r) {
            int m = mt * 16 + quad * 4 + r;
            ucsh[0][m][kout0] = prelu_f(acc[0][mt][0][r] + bc0, ac2);
            ucsh[1][m][kout0] = prelu_f(acc[1][mt][0][r] + bb0, ab2);
            if (has1) {
                ucsh[0][m][kout1] = prelu_f(acc[0][mt][1][r] + bc1v, ac2);
                ucsh[1][m][kout1] = prelu_f(acc[1][mt][1][r] + bb1v, ab2);
            }
        }
    }
    __syncthreads();
    {
        int row = tid >> 3;
        int oc = tid & 7;
        int rg = rowbase + row;
        bool valid = (rg < nrows_tot);
        for (int o = oc; o < NCLS; o += 8) {
            float s = bc2[o];
            const float* w = Wc2 + o * KH;
#pragma unroll 4
            for (int k = 0; k < KH; ++k) s += w[k] * ucsh[0][row][k];
            if (valid) cls_out[rg * NCLS + o] = s;
        }
        // bin: 32 rows x 2 outputs = 64 work items
        if (tid < 64) {
            int row2 = tid >> 1, o = tid & 1;
            int rg2 = rowbase + row2;
            float s = bb2[o];
            const float* w = Wb2 + o * KH;
#pragma unroll 4
            for (int k = 0; k < KH; ++k) s += w[k] * ucsh[1][row2][k];
            if (rg2 < nrows_tot) bin_out[rg2 * 2 + o] = s;
        }
    }
}

// ---------------- K5: scores — conflict-fixed LDS layouts ------------------
#define JT 32
#define JTILES 13
#define NP2 201
#define APS 280         // k_scores A-tile row stride in shorts
#define CIP 264         // padded cish row: FF + FF/32
__global__ __launch_bounds__(256, 3)
void k_scores(const float* __restrict__ cum,
              const short* __restrict__ wfrag,
              const float* __restrict__ pxd, const float* __restrict__ pxe,
              const float* __restrict__ b1p, const float* __restrict__ w2p,
              const float* __restrict__ b2p,
              const float* __restrict__ a1p, const float* __restrict__ a2p,
              float* __restrict__ scores, float* __restrict__ dpcol) {
    int blk = blockIdx.x;
    int jt = blk % JTILES;
    int ipair = (blk / JTILES) % NP2;
    int b = blk / (JTILES * NP2);
    int tid = threadIdx.x;
    float a1 = a1p[0], a2 = a2p[0];
    int jbase = jt * JT;
    int i0 = ipair * 2;
    int i1 = i0 + 1;
    bool has_i1 = (i1 <= SS);
    int i1c = has_i1 ? i1 : i0;

    __shared__ __align__(16) float cish[2][CIP];
    __shared__ __align__(16) short dth[2][JT][APS];
    __shared__ float red[2][4][JT];

    cish[0][tid + (tid >> 5)] = cum[(b * NN + i0) * FF + tid];
    cish[1][tid + (tid >> 5)] = cum[(b * NN + i1c) * FF + tid];
    __syncthreads();

    {
        int row = tid >> 3;
        int fb = (tid & 7) * 32;
        int fbq = fb + (tid & 7);       // padded cish base for this chunk
        int jg = jbase + row;
        int jc = (jg <= SS) ? jg : SS;
        const float* cj = cum + (b * NN + jc) * FF + fb;
        float4 v[8];
#pragma unroll
        for (int c8 = 0; c8 < 4; ++c8) {
            v[2 * c8] = *(const float4*)(cj + c8 * 8);
            v[2 * c8 + 1] = *(const float4*)(cj + c8 * 8 + 4);
        }
#pragma unroll
        for (int ii = 0; ii < 2; ++ii) {
            const float* cio = &cish[ii][0];
#pragma unroll
            for (int c8 = 0; c8 < 4; ++c8) {
                float dv[8] = { v[2*c8].x, v[2*c8].y, v[2*c8].z, v[2*c8].w,
                                v[2*c8+1].x, v[2*c8+1].y, v[2*c8+1].z, v[2*c8+1].w };
                union { short8 s; unsigned short u[8]; } h8;
#pragma unroll
                for (int e = 0; e < 8; ++e) {
                    float d = prelu_f(dv[e] - cio[fbq + c8 * 8 + e], a1);
                    h8.u[e] = f2bf(d);
                }
                *(short8*)(&dth[ii][row][fb + c8 * 8]) = h8.s;
            }
        }
    }
    __syncthreads();

    int lane = tid & 63;
    int wv = tid >> 6;
    int quad = lane >> 4;
    int l15 = lane & 15;
    int kt0 = wv * 2, kt1 = wv * 2 + 1;
    bool has1 = (kt1 < 7);

    const short8* wf = (const short8*)wfrag;
    f32x4 acc[2][2][2];
#pragma unroll
    for (int ii = 0; ii < 2; ++ii)
#pragma unroll
        for (int mt = 0; mt < 2; ++mt)
#pragma unroll
            for (int kk = 0; kk < 2; ++kk) acc[ii][mt][kk] = (f32x4){0.f,0.f,0.f,0.f};

#pragma unroll
    for (int ks = 0; ks < 8; ++ks) {
        short8 b0 = wf[((kt0 * 8 + ks) * 4 + quad) * 16 + l15];
        short8 b1v = has1 ? wf[((kt1 * 8 + ks) * 4 + quad) * 16 + l15] : b0;
#pragma unroll
        for (int ii = 0; ii < 2; ++ii) {
#pragma unroll
            for (int mt = 0; mt < 2; ++mt) {
                short8 a = *(const short8*)(&dth[ii][mt * 16 + l15][ks * 32 + quad * 8]);
                acc[ii][mt][0] = __builtin_amdgcn_mfma_f32_16x16x32_bf16(a, b0, acc[ii][mt][0], 0, 0, 0);
                if (has1)
                    acc[ii][mt][1] = __builtin_amdgcn_mfma_f32_16x16x32_bf16(a, b1v, acc[ii][mt][1], 0, 0, 0);
            }
        }
    }

    int kout0 = kt0 * 16 + l15;
    int kout1 = has1 ? (kt1 * 16 + l15) : 0;
    float bb0 = b1p[kout0], bb1v = b1p[kout1];
    float w20 = w2p[kout0];
    float w21 = has1 ? w2p[kout1] : 0.f;

#pragma unroll
    for (int ii = 0; ii < 2; ++ii) {
        int iv = ii ? i1c : i0;
        float pd0 = pxd[(b * NN + iv) * KP + kout0];
        float pd1 = pxd[(b * NN + iv) * KP + kout1];
#pragma unroll
        for (int mt = 0; mt < 2; ++mt) {
#pragma unroll
            for (int r = 0; r < 4; ++r) {
                int m = mt * 16 + quad * 4 + r;
                int jg = jbase + m;
                int jc = (jg <= SS) ? jg : SS;
                float pe0 = pxe[(b * NN + jc) * KP + kout0];
                float pe1 = pxe[(b * NN + jc) * KP + kout1];
                float h0 = acc[ii][mt][0][r] + pd0 + pe0 + bb0;
                float s = w20 * prelu_f(h0, a2);
                float h1 = acc[ii][mt][1][r] + pd1 + pe1 + bb1v;
                s += w21 * prelu_f(h1, a2);
                s += __shfl_xor(s, 1);
                s += __shfl_xor(s, 2);
                s += __shfl_xor(s, 4);
                s += __shfl_xor(s, 8);
                if (l15 == 0) red[ii][wv][m] = s;
            }
        }
    }
    __syncthreads();
    if (tid < 2 * JT) {
        int ii = tid >> 5;
        int jl = tid & 31;
        int jg = jbase + jl;
        int iv = ii ? i1 : i0;
        if (jg <= SS && (ii == 0 || has_i1)) {
            float tot = red[ii][0][jl] + red[ii][1][jl] + red[ii][2][jl] + red[ii][3][jl] + b2p[0];
            scores[(b * NN + iv) * NN + jg] = tot;
            int d = jg - iv;
            if (d >= 1 && d <= MAXSEG) {
                // rotating-slot layout: slot = iv mod 64 (window<64 => injective)
                dpcol[(b * NN + jg) * 64 + (iv & 63)] = tot;
            }
        }
    }
}

// ---------------- K7: DP v4 — pair-step: two parallel DPP reductions -------
// Steps I and I+1 fused: the I+1 reduction over k in [loB, I-1] is
// independent of best[I], so both 6-level DPP max-chains run interleaved
// (pure ILP). k=I candidate added after via readlane: best[I+1] =
// max(mB, best[I] + col_{I+1}[I]); strict > keeps jnp.argmax first-max
// tie-break (on tie prefer B-side, whose indices are all < I).
__global__ void k_dp(const float* __restrict__ dpcol, const int* __restrict__ lengths,
                     float* __restrict__ predF, float* __restrict__ prevF) {
    int b = blockIdx.x;
    int lane = threadIdx.x;          // 64 threads = 1 wave
    int len = lengths[b];
    if (lane == 0) prevF[b * NN] = 0.f;

    float blr = 0.f;                 // lane l holds best[k] for latest k ≡ l (mod 64)
    float predv = 0.f;

#define LO(I) (((I) > MAXSEG) ? ((I) - MAXSEG) : 0)
#define LOADCOL(ii) \
    ( ((ii) <= SS && (((lane - LO(ii)) & 63) < ((ii) - LO(ii)))) \
        ? dpcol[(b * NN + (ii)) * 64 + lane] : 0.f )

    float u0 = LOADCOL(1), u1 = LOADCOL(2), u2 = LOADCOL(3), u3 = LOADCOL(4);
    float u4 = LOADCOL(5), u5 = LOADCOL(6), u6 = LOADCOL(7), u7 = LOADCOL(8);

#define DPP_MAX2(CTRL, va, vb) do {                                           \
        int _ta = __builtin_amdgcn_update_dpp(__float_as_int(va),             \
                      __float_as_int(va), (CTRL), 0xF, 0xF, false);           \
        int _tb = __builtin_amdgcn_update_dpp(__float_as_int(vb),             \
                      __float_as_int(vb), (CTRL), 0xF, 0xF, false);           \
        (va) = fmaxf((va), __int_as_float(_ta));                              \
        (vb) = fmaxf((vb), __int_as_float(_tb));                              \
    } while (0)

#define DP_STEP2(I, BUFA, BUFB) do {                                          \
        int loA_ = LO(I);                                                     \
        int cntA_ = (I) - loA_;                                               \
        int loB_ = LO((I) + 1);                                               \
        int cntBm_ = (I) - loB_;          /* candidates [loB, I-1] */         \
        int offA_ = (lane - loA_) & 63;                                       \
        int offB_ = (lane - loB_) & 63;                                       \
        float vA0_ = (offA_ < cntA_) ? blr + BUFA : -INFINITY;                \
        float vB0_ = (offB_ < cntBm_) ? blr + BUFB : -INFINITY;               \
        float vA_ = vA0_, vB_ = vB0_;                                         \
        DPP_MAX2(0x111, vA_, vB_);   /* row_shr:1  */                         \
        DPP_MAX2(0x112, vA_, vB_);   /* row_shr:2  */                         \
        DPP_MAX2(0x114, vA_, vB_);   /* row_shr:4  */                         \
        DPP_MAX2(0x118, vA_, vB_);   /* row_shr:8  */                         \
        DPP_MAX2(0x142, vA_, vB_);   /* row_bcast:15 */                       \
        DPP_MAX2(0x143, vA_, vB_);   /* row_bcast:31 */                       \
        float mA_ = __int_as_float(                                           \
            __builtin_amdgcn_readlane(__float_as_int(vA_), 63));              \
        float mB_ = __int_as_float(                                           \
            __builtin_amdgcn_readlane(__float_as_int(vB_), 63));              \
        float sI_ = __int_as_float(                                           \
            __builtin_amdgcn_readlane(__float_as_int(BUFB), (I) & 63));       \
        float candI_ = mA_ + sI_;                                             \
        bool takeI_ = candI_ > mB_;                                           \
        float mBf_ = takeI_ ? candI_ : mB_;                                   \
        unsigned long long mkA_ = __ballot(vA0_ == mA_);                      \
        unsigned long long mkB_ = __ballot(vB0_ == mB_);                      \
        int rotA_ = loA_ & 63;                                                \
        int rotB_ = loB_ & 63;                                                \
        unsigned long long mrA_ = rotA_ ? ((mkA_ >> rotA_) | (mkA_ << (64 - rotA_))) : mkA_; \
        unsigned long long mrB_ = rotB_ ? ((mkB_ >> rotB_) | (mkB_ << (64 - rotB_))) : mkB_; \
        int kbA_ = loA_ + (__ffsll(mrA_) - 1);                                \
        int kbB_ = takeI_ ? (I) : (loB_ + (__ffsll(mrB_) - 1));               \
        if (lane == 0) {                                                      \
            prevF[b * NN + (I)] = (float)kbA_;                                \
            prevF[b * NN + (I) + 1] = (float)kbB_;                            \
            if ((I) == len) predv = mA_;                                      \
            if ((I) + 1 == len) predv = mBf_;                                 \
        }                                                                     \
        if (lane == ((I) & 63)) blr = mA_;                                    \
        if (lane == (((I) + 1) & 63)) blr = mBf_;                             \
    } while (0)

    for (int i = 1; i <= SS; i += 8) {
        DP_STEP2(i,     u0, u1); u0 = LOADCOL(i + 8);  u1 = LOADCOL(i + 9);
        DP_STEP2(i + 2, u2, u3); u2 = LOADCOL(i + 10); u3 = LOADCOL(i + 11);
        DP_STEP2(i + 4, u4, u5); u4 = LOADCOL(i + 12); u5 = LOADCOL(i + 13);
        DP_STEP2(i + 6, u6, u7); u6 = LOADCOL(i + 14); u7 = LOADCOL(i + 15);
    }
#undef DP_STEP2
#undef DPP_MAX2
#undef LOADCOL
#undef LO
    if (lane == 0) predF[b] = predv;
}

// ---------------- launch ---------------------------------------------------
extern "C" void kernel_launch(void* const* d_in, const int* in_sizes, int n_in,
                              void* d_out, int out_size, void* d_ws, size_t ws_size,
                              hipStream_t stream) {
    const float* x    = (const float*)d_in[0];
    const int* lengths= (const int*)d_in[1];
    const float* Wi_f = (const float*)d_in[2];
    const float* Wh_f = (const float*)d_in[3];
    const float* b_f  = (const float*)d_in[4];
    const float* Wi_b = (const float*)d_in[5];
    const float* Wh_b = (const float*)d_in[6];
    const float* b_b  = (const float*)d_in[7];
    const float* a1   = (const float*)d_in[8];
    const float* W1   = (const float*)d_in[9];
    const float* b1   = (const float*)d_in[10];
    const float* a2   = (const float*)d_in[11];
    const float* W2   = (const float*)d_in[12];
    const float* b2   = (const float*)d_in[13];
    const float* ac1  = (const float*)d_in[14];
    const float* Wc1  = (const float*)d_in[15];
    const float* bc1  = (const float*)d_in[16];
    const float* ac2  = (const float*)d_in[17];
    const float* Wc2  = (const float*)d_in[18];
    const float* bc2  = (const float*)d_in[19];
    const float* ab1  = (const float*)d_in[20];
    const float* Wb1  = (const float*)d_in[21];
    const float* bb1  = (const float*)d_in[22];
    const float* ab2  = (const float*)d_in[23];
    const float* Wb2  = (const float*)d_in[24];
    const float* bb2  = (const float*)d_in[25];

    float* out = (float*)d_out;
    float* scores = out + SCORES_OFF;
    float* cls    = out + CLS_OFF;
    float* bin    = out + BIN_OFF;
    float* pred   = out + PRED_OFF;
    float* prev   = out + PREV_OFF;

    float* ws    = (float*)d_ws;
    float* gx    = ws + WS_GX;
    float* dpcol = ws + WS_GX;       // reuse: gx dead after k_lstm_rec
    float* rnn   = ws + WS_RNN;
    float* cum   = ws + WS_CUM;
    float* pxd   = ws + WS_PXD;
    float* pxe   = ws + WS_PXE;
    float* w2p   = ws + WS_W2P;
    float* b1p   = ws + WS_B1P;
    __half* whp  = (__half*)(ws + WS_WHP);
    short* wfC   = (short*)(ws + WS_WFRAGC);
    short* wfD   = (short*)(ws + WS_WFRAGD);
    short* wfE   = (short*)(ws + WS_WFRAGE);
    short* wfHC  = (short*)(ws + WS_WFRAGHC);
    short* wfHB  = (short*)(ws + WS_WFRAGHB);
    float* bc1p  = ws + WS_BC1P;
    float* bb1p  = ws + WS_BB1P;

    k_lstm_pre<<<PREPBLKS, 256, 0, stream>>>(x, Wi_f, b_f, Wi_b, b_b, gx,
                                             Wh_f, Wh_b, whp);
    k_lstm_rec<<<4 + WPACKS, 256, 0, stream>>>((const _Float16*)whp, gx, rnn,
                                               W1, W2, b1, Wc1, Wb1, bc1, bb1,
                                               wfC, wfD, wfE, wfHC, wfHB,
                                               w2p, b1p, bc1p, bb1p);
    k_cum_mlp<<<BB + PXBLKS + HDBLKS, 256, 0, stream>>>(rnn, cum, a1, ac1, ab1,
                                                        wfD, wfE, wfHC, wfHB,
                                                        bc1p, bb1p, ac2, ab2,
                                                        Wc2, bc2, Wb2, bb2,
                                                        pxd, pxe, cls, bin);
    k_scores<<<BB * NP2 * JTILES, 256, 0, stream>>>(cum, wfC, pxd, pxe, b1p, w2p, b2,
                                                    a1, a2, scores, dpcol);
    k_dp<<<BB, 64, 0, stream>>>(dpcol, lengths, pred, prev);
}

// Round 12
// 522.096 us; speedup vs baseline: 1.1112x; 1.0111x over previous
//
#include <hip/hip_runtime.h>
#include <hip/hip_fp16.h>
#include <math.h>

// Problem constants
#define BB 2
#define SS 400
#define II 80
#define HH 128
#define FF 256          // 2*H
#define NN 401          // S+1
#define G4 512          // 4*H
#define MAXSEG 50
#define NCLS 50
#define KH 100          // rows of W1 / Wc1 / Wb1
#define KP 112          // KH padded to 7*16 for MFMA
#define FRAGF 14336     // floats per frag-packed W (28672 shorts)

// d_out layout (floats): scores | cls | bin | pred | prev
#define SCORES_OFF 0
#define CLS_OFF    (BB*NN*NN)
#define BIN_OFF    (CLS_OFF + BB*SS*NCLS)
#define PRED_OFF   (BIN_OFF + BB*SS*2)
#define PREV_OFF   (PRED_OFF + BB)

// workspace layout (float slots)
#define WS_GX      0                          // 819200; dead after rec -> dpcol (51328)
#define WS_RNN     (WS_GX + 4*SS*G4)          // B*S*F
#define WS_CUM     (WS_RNN + BB*SS*FF)        // B*N*F
#define WS_PXD     (WS_CUM + BB*NN*FF)        // B*N*KP
#define WS_PXE     (WS_PXD + BB*NN*KP)
#define WS_PART    (WS_PXE + BB*NN*KP)        // B*16*F (unused since cum fusion)
#define WS_W2P     (WS_PART + BB*16*FF)       // KP
#define WS_B1P     (WS_W2P + KP)              // KP
#define WS_WHP     (WS_B1P + KP)              // Wh f16 MFMA frags: 131072 halfs
#define WS_WFRAGC  (WS_WHP + 65536)
#define WS_WFRAGD  (WS_WFRAGC + FRAGF)
#define WS_WFRAGE  (WS_WFRAGD + FRAGF)
#define WS_WFRAGHC (WS_WFRAGE + FRAGF)
#define WS_WFRAGHB (WS_WFRAGHC + FRAGF)
#define WS_BC1P    (WS_WFRAGHB + FRAGF)       // KP
#define WS_BB1P    (WS_BC1P + KP)             // KP

typedef __attribute__((ext_vector_type(8))) short short8;
typedef __attribute__((ext_vector_type(4))) float f32x4;
typedef _Float16 f16x2 __attribute__((ext_vector_type(2)));
typedef _Float16 f16x8 __attribute__((ext_vector_type(8)));

__device__ __forceinline__ float prelu_f(float x, float a) {
    return x >= 0.f ? x : a * x;
}
__device__ __forceinline__ unsigned short f2bf(float x) {
    union { float f; unsigned u; } v; v.f = x;
    unsigned r = v.u + 0x7fffu + ((v.u >> 16) & 1u);   // RNE
    return (unsigned short)(r >> 16);
}
// HW RNE pack: 2 f32 -> 1 u32 of 2 bf16 (low = lo). Identical rounding to
// f2bf, 1 instr instead of ~8. No builtin on gfx950 -> inline asm (T12).
__device__ __forceinline__ unsigned cvt_pk_bf16(float lo, float hi) {
    unsigned r;
    asm("v_cvt_pk_bf16_f32 %0, %1, %2" : "=v"(r) : "v"(lo), "v"(hi));
    return r;
}
__device__ __forceinline__ float fast_sigmoid(float x) {
    return 1.f / (1.f + __expf(-x));
}
__device__ __forceinline__ float fast_tanh(float x) {
    return 1.f - 2.f / (1.f + __expf(2.f * x));
}
// m201-style barrier: LDS drained, but vmcnt (global loads/stores) stays
// in flight across the barrier — no "memory" clobber, no vmcnt drain.
__device__ __forceinline__ void rec_barrier() {
    __builtin_amdgcn_sched_barrier(0);
    asm volatile("s_waitcnt lgkmcnt(0)");
    __builtin_amdgcn_s_barrier();
    __builtin_amdgcn_sched_barrier(0);
}
__device__ __forceinline__ int fragidx(int k, int f) {
    int kt = k >> 4, l15 = k & 15;
    int ks = f >> 5, quad = (f >> 3) & 3, e = f & 7;
    return ((((kt * 8 + ks) * 4 + quad) * 16) + l15) * 8 + e;
}

// ---------------- K1: prep — whp pack (blk<512) + gx (Wi-reuse tiles) ------
#define GXTC 8
#define GXBLKS (4 * (SS / GXTC))      // 200
#define PREPBLKS (G4 + GXBLKS)
__global__ void k_lstm_pre(const float* __restrict__ x,
                           const float* __restrict__ Wi_f, const float* __restrict__ b_f,
                           const float* __restrict__ Wi_b, const float* __restrict__ b_b,
                           float* __restrict__ gx,
                           const float* __restrict__ Wh_f, const float* __restrict__ Wh_b,
                           __half* __restrict__ whp) {
    int blk0 = blockIdx.x;
    int tid = threadIdx.x;
    if (blk0 < G4) {
        // Pack Wh into fp16 MFMA B-fragments for mfma_f32_16x16x32_f16.
        int gq = blk0;                   // 0..511 = gate*128 + unit
        int gate = gq >> 7;
        int unit = gq & 127;
        int wv = unit >> 4, col = unit & 15;
        int dir = tid >> 7, k = tid & 127;
        int kt = k >> 5, lanehi = (k >> 3) & 3, e = k & 7;
        int lane = lanehi * 16 + col;
        const float* Wh = dir ? Wh_b : Wh_f;
        whp[(size_t)(((((dir * 4 + gate) * 8 + wv) * 4 + kt) * 64) + lane) * 8 + e] =
            (__half)Wh[gq * HH + k];
        return;
    }
    int gxb = blk0 - G4;               // 0..199
    int db = gxb / (SS / GXTC);
    int tc = gxb % (SS / GXTC);
    int b = db & 1, dir = db >> 1;
    const float* Wi = dir ? Wi_b : Wi_f;
    const float* bias = dir ? b_b : b_f;
    int t0 = tc * GXTC;

    __shared__ __align__(16) float xs[GXTC][II];
    for (int idx = tid; idx < GXTC * II; idx += 256) {
        int tt = idx / II, ii = idx - tt * II;
        int xt = dir ? (SS - 1 - (t0 + tt)) : (t0 + tt);
        xs[tt][ii] = x[(b * SS + xt) * II + ii];
    }
    __syncthreads();

    int g1 = tid + 256;
    const float* w0p = Wi + tid * II;
    const float* w1p = Wi + g1 * II;
    float acc0[GXTC], acc1[GXTC];
    {
        float b0v = bias[tid], b1v = bias[g1];
#pragma unroll
        for (int t = 0; t < GXTC; ++t) { acc0[t] = b0v; acc1[t] = b1v; }
    }
    for (int kc = 0; kc < 5; ++kc) {          // 5 chunks of 16 k
        float4 wa0 = *(const float4*)(w0p + kc * 16 + 0);
        float4 wa1 = *(const float4*)(w0p + kc * 16 + 4);
        float4 wa2 = *(const float4*)(w0p + kc * 16 + 8);
        float4 wa3 = *(const float4*)(w0p + kc * 16 + 12);
        float4 wb0 = *(const float4*)(w1p + kc * 16 + 0);
        float4 wb1 = *(const float4*)(w1p + kc * 16 + 4);
        float4 wb2 = *(const float4*)(w1p + kc * 16 + 8);
        float4 wb3 = *(const float4*)(w1p + kc * 16 + 12);
#pragma unroll
        for (int t = 0; t < GXTC; ++t) {
            float4 x0 = *(const float4*)(&xs[t][kc * 16 + 0]);
            float4 x1 = *(const float4*)(&xs[t][kc * 16 + 4]);
            float4 x2 = *(const float4*)(&xs[t][kc * 16 + 8]);
            float4 x3 = *(const float4*)(&xs[t][kc * 16 + 12]);
            acc0[t] += wa0.x * x0.x + wa0.y * x0.y + wa0.z * x0.z + wa0.w * x0.w;
            acc0[t] += wa1.x * x1.x + wa1.y * x1.y + wa1.z * x1.z + wa1.w * x1.w;
            acc0[t] += wa2.x * x2.x + wa2.y * x2.y + wa2.z * x2.z + wa2.w * x2.w;
            acc0[t] += wa3.x * x3.x + wa3.y * x3.y + wa3.z * x3.z + wa3.w * x3.w;
            acc1[t] += wb0.x * x0.x + wb0.y * x0.y + wb0.z * x0.z + wb0.w * x0.w;
            acc1[t] += wb1.x * x1.x + wb1.y * x1.y + wb1.z * x1.z + wb1.w * x1.w;
            acc1[t] += wb2.x * x2.x + wb2.y * x2.y + wb2.z * x2.z + wb2.w * x2.w;
            acc1[t] += wb3.x * x3.x + wb3.y * x3.y + wb3.z * x3.z + wb3.w * x3.w;
        }
    }
    // layout [db][t][unit][gate] so rec reads one float4 per lane
#pragma unroll
    for (int t = 0; t < GXTC; ++t) {
        gx[((size_t)(db * SS + t0 + t) * HH + (tid & 127)) * 4 + (tid >> 7)] = acc0[t];
        gx[((size_t)(db * SS + t0 + t) * HH + (g1 & 127)) * 4 + (g1 >> 7)] = acc1[t];
    }
}

// ---------------- K2: rec v7 (chains, blk<4) + W-frag packing (blk>=4) -----
#define WPACKS (5 * KP)
__global__ __launch_bounds__(256, 1)
void k_lstm_rec(const _Float16* __restrict__ whf, const float* __restrict__ gxr,
                float* __restrict__ rnn_out,
                const float* __restrict__ W1, const float* __restrict__ W2,
                const float* __restrict__ b1,
                const float* __restrict__ Wc1, const float* __restrict__ Wb1,
                const float* __restrict__ bc1, const float* __restrict__ bb1,
                short* __restrict__ wfC, short* __restrict__ wfD,
                short* __restrict__ wfE, short* __restrict__ wfHC,
                short* __restrict__ wfHB,
                float* __restrict__ w2p, float* __restrict__ b1p,
                float* __restrict__ bc1p, float* __restrict__ bb1p) {
    int tid = threadIdx.x;
    if (blockIdx.x >= 4) {
        int blk0 = blockIdx.x - 4;       // 0..559
        int which = blk0 / KP;
        int k = blk0 % KP;
        float w = 0.f;
        short* dst = wfC;
        if (which == 0)      { if (k < KH) w = W1[k * (3 * FF) + tid];          dst = wfC; }
        else if (which == 1) { if (k < KH) w = W1[k * (3 * FF) + FF + tid];     dst = wfD; }
        else if (which == 2) { if (k < KH) w = W1[k * (3 * FF) + 2 * FF + tid]; dst = wfE; }
        else if (which == 3) { if (k < KH) w = Wc1[k * FF + tid];               dst = wfHC; }
        else                 { if (k < KH) w = Wb1[k * FF + tid];               dst = wfHB; }
        dst[fragidx(k, tid)] = (short)f2bf(w);
        if (tid == 0) {
            if (which == 0) {
                w2p[k] = (k < KH) ? W2[k] : 0.f;
                b1p[k] = (k < KH) ? b1[k] : 0.f;
            } else if (which == 3) {
                bc1p[k] = (k < KH) ? bc1[k] : 0.f;
            } else if (which == 4) {
                bb1p[k] = (k < KH) ? bb1[k] : 0.f;
            }
        }
        return;
    }
    int db = blockIdx.x;
    int b = db & 1, dir = db >> 1;
    int wv = tid >> 6;              // 0..3
    int lane = tid & 63;

    // B frags for the wave's two 16-unit groups (packed groups 2wv, 2wv+1)
    f16x8 bfA[4][4], bfB[4][4];
    {
        const f16x8* wp = (const f16x8*)whf;
#pragma unroll
        for (int g = 0; g < 4; ++g)
#pragma unroll
            for (int kt = 0; kt < 4; ++kt) {
                bfA[g][kt] = wp[((((dir * 4 + g) * 8 + (2 * wv)) * 4 + kt) * 64) + lane];
                bfB[g][kt] = wp[((((dir * 4 + g) * 8 + (2 * wv + 1)) * 4 + kt) * 64) + lane];
            }
    }

    __shared__ __align__(16) __half hsf[2][128];
    (&hsf[0][0])[tid] = (__half)0.f;           // 256 entries, 256 threads
    __syncthreads();

    bool act = (lane < 32);
    bool grpB = (lane >= 16);                  // within act: group select
    int unit = (wv << 5) + (lane & 31);        // valid for act lanes
    float c_state = 0.f;

    const float4* gp4 = (const float4*)gxr + (size_t)(db * SS) * HH + unit;
    float4 g0 = make_float4(0,0,0,0), g1 = g0, g2 = g0, g3 = g0;
    if (act) {
        g0 = gp4[0 * HH];
        g1 = gp4[1 * HH];
        g2 = gp4[2 * HH];
        g3 = gp4[3 * HH];
    }
    const float4* gq = gp4 + (size_t)4 * HH;   // marching prefetch cursor

    float* outp = rnn_out + ((size_t)b * SS + (dir ? (SS - 1) : 0)) * FF
                + dir * HH + unit;             // consumed only by act lanes
    const int ostep = dir ? -FF : FF;

    const f32x4 z4 = (f32x4){0.f, 0.f, 0.f, 0.f};
    int pb = 0;
    int hib = (lane >> 4) * 8;                 // k-chunk base within ktile
    bool aload = (lane & 3) == 0;              // A rows 0,4,8,12 hold h

    f16x8 a0v = (f16x8)(_Float16)0.f, a1v = a0v, a2v = a0v, a3v = a0v;

#define REC_STEP(G, PF) do {                                                   \
        if (aload) {                                                           \
            a0v = *(const f16x8*)(&hsf[pb][ 0 + hib]);                         \
            a1v = *(const f16x8*)(&hsf[pb][32 + hib]);                         \
            a2v = *(const f16x8*)(&hsf[pb][64 + hib]);                         \
            a3v = *(const f16x8*)(&hsf[pb][96 + hib]);                         \
        }                                                                      \
        f32x4 aA0 = __builtin_amdgcn_mfma_f32_16x16x32_f16(a0v, bfA[0][0], z4, 0, 0, 0); \
        f32x4 aA1 = __builtin_amdgcn_mfma_f32_16x16x32_f16(a0v, bfA[1][0], z4, 0, 0, 0); \
        f32x4 aA2 = __builtin_amdgcn_mfma_f32_16x16x32_f16(a0v, bfA[2][0], z4, 0, 0, 0); \
        f32x4 aA3 = __builtin_amdgcn_mfma_f32_16x16x32_f16(a0v, bfA[3][0], z4, 0, 0, 0); \
        f32x4 aB0 = __builtin_amdgcn_mfma_f32_16x16x32_f16(a0v, bfB[0][0], z4, 0, 0, 0); \
        f32x4 aB1 = __builtin_amdgcn_mfma_f32_16x16x32_f16(a0v, bfB[1][0], z4, 0, 0, 0); \
        f32x4 aB2 = __builtin_amdgcn_mfma_f32_16x16x32_f16(a0v, bfB[2][0], z4, 0, 0, 0); \
        f32x4 aB3 = __builtin_amdgcn_mfma_f32_16x16x32_f16(a0v, bfB[3][0], z4, 0, 0, 0); \
        aA0 = __builtin_amdgcn_mfma_f32_16x16x32_f16(a1v, bfA[0][1], aA0, 0, 0, 0); \
        aA1 = __builtin_amdgcn_mfma_f32_16x16x32_f16(a1v, bfA[1][1], aA1, 0, 0, 0); \
        aA2 = __builtin_amdgcn_mfma_f32_16x16x32_f16(a1v, bfA[2][1], aA2, 0, 0, 0); \
        aA3 = __builtin_amdgcn_mfma_f32_16x16x32_f16(a1v, bfA[3][1], aA3, 0, 0, 0); \
        aB0 = __builtin_amdgcn_mfma_f32_16x16x32_f16(a1v, bfB[0][1], aB0, 0, 0, 0); \
        aB1 = __builtin_amdgcn_mfma_f32_16x16x32_f16(a1v, bfB[1][1], aB1, 0, 0, 0); \
        aB2 = __builtin_amdgcn_mfma_f32_16x16x32_f16(a1v, bfB[2][1], aB2, 0, 0, 0); \
        aB3 = __builtin_amdgcn_mfma_f32_16x16x32_f16(a1v, bfB[3][1], aB3, 0, 0, 0); \
        aA0 = __builtin_amdgcn_mfma_f32_16x16x32_f16(a2v, bfA[0][2], aA0, 0, 0, 0); \
        aA1 = __builtin_amdgcn_mfma_f32_16x16x32_f16(a2v, bfA[1][2], aA1, 0, 0, 0); \
        aA2 = __builtin_amdgcn_mfma_f32_16x16x32_f16(a2v, bfA[2][2], aA2, 0, 0, 0); \
        aA3 = __builtin_amdgcn_mfma_f32_16x16x32_f16(a2v, bfA[3][2], aA3, 0, 0, 0); \
        aB0 = __builtin_amdgcn_mfma_f32_16x16x32_f16(a2v, bfB[0][2], aB0, 0, 0, 0); \
        aB1 = __builtin_amdgcn_mfma_f32_16x16x32_f16(a2v, bfB[1][2], aB1, 0, 0, 0); \
        aB2 = __builtin_amdgcn_mfma_f32_16x16x32_f16(a2v, bfB[2][2], aB2, 0, 0, 0); \
        aB3 = __builtin_amdgcn_mfma_f32_16x16x32_f16(a2v, bfB[3][2], aB3, 0, 0, 0); \
        aA0 = __builtin_amdgcn_mfma_f32_16x16x32_f16(a3v, bfA[0][3], aA0, 0, 0, 0); \
        aA1 = __builtin_amdgcn_mfma_f32_16x16x32_f16(a3v, bfA[1][3], aA1, 0, 0, 0); \
        aA2 = __builtin_amdgcn_mfma_f32_16x16x32_f16(a3v, bfA[2][3], aA2, 0, 0, 0); \
        aA3 = __builtin_amdgcn_mfma_f32_16x16x32_f16(a3v, bfA[3][3], aA3, 0, 0, 0); \
        aB0 = __builtin_amdgcn_mfma_f32_16x16x32_f16(a3v, bfB[0][3], aB0, 0, 0, 0); \
        aB1 = __builtin_amdgcn_mfma_f32_16x16x32_f16(a3v, bfB[1][3], aB1, 0, 0, 0); \
        aB2 = __builtin_amdgcn_mfma_f32_16x16x32_f16(a3v, bfB[2][3], aB2, 0, 0, 0); \
        aB3 = __builtin_amdgcn_mfma_f32_16x16x32_f16(a3v, bfB[3][3], aB3, 0, 0, 0); \
        if (act) {                                                             \
            float gi = (grpB ? aB0[0] : aA0[0]) + G.x;                         \
            float gf = (grpB ? aB1[0] : aA1[0]) + G.y;                         \
            float gg = (grpB ? aB2[0] : aA2[0]) + G.z;                         \
            float go = (grpB ? aB3[0] : aA3[0]) + G.w;                         \
            if (PF) { G = *gq; gq += HH; }    /* reissue prefetch (t+4) */     \
            c_state = fast_sigmoid(gf) * c_state + fast_sigmoid(gi) * fast_tanh(gg); \
            float h = fast_sigmoid(go) * fast_tanh(c_state);                   \
            hsf[pb ^ 1][unit] = (__half)h;                                     \
            *outp = h;                                                         \
            outp += ostep;                                                     \
        }                                                                      \
        rec_barrier();                                                         \
        pb ^= 1;                                                               \
    } while (0)

    for (int it = 0; it < 99; ++it) {          // steps 0..395, prefetch valid
        REC_STEP(g0, 1);
        REC_STEP(g1, 1);
        REC_STEP(g2, 1);
        REC_STEP(g3, 1);
    }
    // epilogue: steps 396..399, no prefetch
    REC_STEP(g0, 0);
    REC_STEP(g1, 0);
    REC_STEP(g2, 0);
    REC_STEP(g3, 0);
#undef REC_STEP
}

// ---------------- K4: fused cum (blocks 0..1) + MFMA mlp (blocks 2..52) ----
#define PXBLKS 26
#define HDBLKS 25
#define AP 272          // k_mlp A-tile row stride in shorts
#define UCP 116         // uc tile row stride in floats
__global__ __launch_bounds__(256, 2)
void k_cum_mlp(const float* __restrict__ rnn, float* __restrict__ cum,
               const float* __restrict__ a1p,
               const float* __restrict__ ac1p, const float* __restrict__ ab1p,
               const short* __restrict__ wfD, const short* __restrict__ wfE,
               const short* __restrict__ wfHC, const short* __restrict__ wfHB,
               const float* __restrict__ bc1p, const float* __restrict__ bb1p,
               const float* __restrict__ ac2p, const float* __restrict__ ab2p,
               const float* __restrict__ Wc2, const float* __restrict__ bc2,
               const float* __restrict__ Wb2, const float* __restrict__ bb2,
               float* __restrict__ pxd, float* __restrict__ pxe,
               float* __restrict__ cls_out, float* __restrict__ bin_out) {
    int tid = threadIdx.x;
    if (blockIdx.x < BB) {
        // ---- cumsum over time: single fused sequential scan
        int b = blockIdx.x;
        int f = tid;                // 256 threads
        float run = 0.f;
        cum[(size_t)(b * NN) * FF + f] = 0.f;      // xp row 0 = zeros
        const float* rp = rnn + (size_t)b * SS * FF + f;
        float* cp = cum + ((size_t)b * NN + 1) * FF + f;
#pragma unroll 8
        for (int t = 0; t < SS; ++t) {
            run += rp[(size_t)t * FF];
            cp[(size_t)t * FF] = run;
        }
        return;
    }
    int blk = blockIdx.x - BB;
    bool is_px = (blk < PXBLKS);
    int rowbase = is_px ? blk * 32 : (blk - PXBLKS) * 32;
    int nrows_tot = is_px ? BB * NN : BB * SS;

    __shared__ __align__(16) short dth[2][32][AP];
    __shared__ float ucsh[2][32][UCP];

    // ---- build A tiles (rows = data rows); HW cvt_pk for bf16 pack
    {
        int row = tid >> 3;
        int fb = (tid & 7) * 32;
        int rg = rowbase + row;
        float src[32];
        if (is_px) {
            float a1 = a1p[0];
            int b = rg / NN, n = rg % NN;
            bool valid = (rg < nrows_tot) && (n > 0);
            const float* sp = valid ? (rnn + (b * SS + n - 1) * FF + fb) : nullptr;
#pragma unroll
            for (int c4 = 0; c4 < 8; ++c4) {
                float4 v = valid ? *(const float4*)(sp + c4 * 4) : make_float4(0,0,0,0);
                src[c4*4] = v.x; src[c4*4+1] = v.y; src[c4*4+2] = v.z; src[c4*4+3] = v.w;
            }
            union { short8 s; unsigned u4[4]; } h8;
#pragma unroll
            for (int c8 = 0; c8 < 4; ++c8) {
                float d[8];
#pragma unroll
                for (int e = 0; e < 8; ++e) d[e] = prelu_f(src[c8*8+e], a1);
#pragma unroll
                for (int p = 0; p < 4; ++p) h8.u4[p] = cvt_pk_bf16(d[2*p], d[2*p+1]);
                *(short8*)(&dth[0][row][fb + c8 * 8]) = h8.s;
            }
        } else {
            float ac1 = ac1p[0], ab1 = ab1p[0];
            bool valid = (rg < nrows_tot);
            const float* sp = valid ? (rnn + rg * FF + fb) : nullptr;
#pragma unroll
            for (int c4 = 0; c4 < 8; ++c4) {
                float4 v = valid ? *(const float4*)(sp + c4 * 4) : make_float4(0,0,0,0);
                src[c4*4] = v.x; src[c4*4+1] = v.y; src[c4*4+2] = v.z; src[c4*4+3] = v.w;
            }
            union { short8 s; unsigned u4[4]; } hc, hb;
#pragma unroll
            for (int c8 = 0; c8 < 4; ++c8) {
                float dc[8], dbv[8];
#pragma unroll
                for (int e = 0; e < 8; ++e) {
                    dc[e] = prelu_f(src[c8*8+e], ac1);
                    dbv[e] = prelu_f(src[c8*8+e], ab1);
                }
#pragma unroll
                for (int p = 0; p < 4; ++p) {
                    hc.u4[p] = cvt_pk_bf16(dc[2*p], dc[2*p+1]);
                    hb.u4[p] = cvt_pk_bf16(dbv[2*p], dbv[2*p+1]);
                }
                *(short8*)(&dth[0][row][fb + c8 * 8]) = hc.s;
                *(short8*)(&dth[1][row][fb + c8 * 8]) = hb.s;
            }
        }
    }
    __syncthreads();

    int lane = tid & 63;
    int wv = tid >> 6;
    int quad = lane >> 4;
    int l15 = lane & 15;
    int kt0 = wv * 2, kt1 = wv * 2 + 1;
    bool has1 = (kt1 < 7);

    const short8* wp0 = (const short8*)(is_px ? wfD : wfHC);
    const short8* wp1 = (const short8*)(is_px ? wfE : wfHB);

    // acc[path][mt][kt]
    f32x4 acc[2][2][2];
#pragma unroll
    for (int p = 0; p < 2; ++p)
#pragma unroll
        for (int mt = 0; mt < 2; ++mt)
#pragma unroll
            for (int kk = 0; kk < 2; ++kk) acc[p][mt][kk] = (f32x4){0.f,0.f,0.f,0.f};

#pragma unroll
    for (int ks = 0; ks < 8; ++ks) {
        short8 b00 = wp0[((kt0 * 8 + ks) * 4 + quad) * 16 + l15];
        short8 b01 = has1 ? wp0[((kt1 * 8 + ks) * 4 + quad) * 16 + l15] : b00;
        short8 b10 = wp1[((kt0 * 8 + ks) * 4 + quad) * 16 + l15];
        short8 b11 = has1 ? wp1[((kt1 * 8 + ks) * 4 + quad) * 16 + l15] : b10;
#pragma unroll
        for (int mt = 0; mt < 2; ++mt) {
            short8 a0 = *(const short8*)(&dth[0][mt * 16 + l15][ks * 32 + quad * 8]);
            short8 a1v = is_px ? a0
                       : *(const short8*)(&dth[1][mt * 16 + l15][ks * 32 + quad * 8]);
            acc[0][mt][0] = __builtin_amdgcn_mfma_f32_16x16x32_bf16(a0, b00, acc[0][mt][0], 0, 0, 0);
            acc[1][mt][0] = __builtin_amdgcn_mfma_f32_16x16x32_bf16(a1v, b10, acc[1][mt][0], 0, 0, 0);
            if (has1) {
                acc[0][mt][1] = __builtin_amdgcn_mfma_f32_16x16x32_bf16(a0, b01, acc[0][mt][1], 0, 0, 0);
                acc[1][mt][1] = __builtin_amdgcn_mfma_f32_16x16x32_bf16(a1v, b11, acc[1][mt][1], 0, 0, 0);
            }
        }
    }

    int kout0 = kt0 * 16 + l15;
    int kout1 = has1 ? (kt1 * 16 + l15) : 0;

    if (is_px) {
#pragma unroll
        for (int mt = 0; mt < 2; ++mt) {
#pragma unroll
            for (int r = 0; r < 4; ++r) {
                int m = mt * 16 + quad * 4 + r;
                int rg = rowbase + m;
                if (rg < nrows_tot) {
                    pxd[rg * KP + kout0] = acc[0][mt][0][r];
                    pxe[rg * KP + kout0] = acc[1][mt][0][r];
                    if (has1) {
                        pxd[rg * KP + kout1] = acc[0][mt][1][r];
                        pxe[rg * KP + kout1] = acc[1][mt][1][r];
                    }
                }
            }
        }
        return;
    }

    // heads: layer1 activation -> LDS, then layer2 matvecs
    float bc0 = bc1p[kout0], bc1v = bc1p[kout1];
    float bb0 = bb1p[kout0], bb1v = bb1p[kout1];
    float ac2 = ac2p[0], ab2 = ab2p[0];
#pragma unroll
    for (int mt = 0; mt < 2; ++mt) {
#pragma unroll
        for (int r = 0; r < 4; ++r) {
            int m = mt * 16 + quad * 4 + r;
            ucsh[0][m][kout0] = prelu_f(acc[0][mt][0][r] + bc0, ac2);
            ucsh[1][m][kout0] = prelu_f(acc[1][mt][0][r] + bb0, ab2);
            if (has1) {
                ucsh[0][m][kout1] = prelu_f(acc[0][mt][1][r] + bc1v, ac2);
                ucsh[1][m][kout1] = prelu_f(acc[1][mt][1][r] + bb1v, ab2);
            }
        }
    }
    __syncthreads();
    {
        int row = tid >> 3;
        int oc = tid & 7;
        int rg = rowbase + row;
        bool valid = (rg < nrows_tot);
        for (int o = oc; o < NCLS; o += 8) {
            float s = bc2[o];
            const float* w = Wc2 + o * KH;
#pragma unroll 4
            for (int k = 0; k < KH; ++k) s += w[k] * ucsh[0][row][k];
            if (valid) cls_out[rg * NCLS + o] = s;
        }
        // bin: 32 rows x 2 outputs = 64 work items
        if (tid < 64) {
            int row2 = tid >> 1, o = tid & 1;
            int rg2 = rowbase + row2;
            float s = bb2[o];
            const float* w = Wb2 + o * KH;
#pragma unroll 4
            for (int k = 0; k < KH; ++k) s += w[k] * ucsh[1][row2][k];
            if (rg2 < nrows_tot) bin_out[rg2 * 2 + o] = s;
        }
    }
}

// ---------------- K5: scores — conflict-fixed LDS + HW bf16 pack -----------
#define JT 32
#define JTILES 13
#define NP2 201
#define APS 280         // k_scores A-tile row stride in shorts
#define CIP 264         // padded cish row: FF + FF/32
__global__ __launch_bounds__(256, 3)
void k_scores(const float* __restrict__ cum,
              const short* __restrict__ wfrag,
              const float* __restrict__ pxd, const float* __restrict__ pxe,
              const float* __restrict__ b1p, const float* __restrict__ w2p,
              const float* __restrict__ b2p,
              const float* __restrict__ a1p, const float* __restrict__ a2p,
              float* __restrict__ scores, float* __restrict__ dpcol) {
    int blk = blockIdx.x;
    int jt = blk % JTILES;
    int ipair = (blk / JTILES) % NP2;
    int b = blk / (JTILES * NP2);
    int tid = threadIdx.x;
    float a1 = a1p[0], a2 = a2p[0];
    int jbase = jt * JT;
    int i0 = ipair * 2;
    int i1 = i0 + 1;
    bool has_i1 = (i1 <= SS);
    int i1c = has_i1 ? i1 : i0;

    __shared__ __align__(16) float cish[2][CIP];
    __shared__ __align__(16) short dth[2][JT][APS];
    __shared__ float red[2][4][JT];

    cish[0][tid + (tid >> 5)] = cum[(b * NN + i0) * FF + tid];
    cish[1][tid + (tid >> 5)] = cum[(b * NN + i1c) * FF + tid];
    __syncthreads();

    {
        int row = tid >> 3;
        int fb = (tid & 7) * 32;
        int fbq = fb + (tid & 7);       // padded cish base for this chunk
        int jg = jbase + row;
        int jc = (jg <= SS) ? jg : SS;
        const float* cj = cum + (b * NN + jc) * FF + fb;
        float4 v[8];
#pragma unroll
        for (int c8 = 0; c8 < 4; ++c8) {
            v[2 * c8] = *(const float4*)(cj + c8 * 8);
            v[2 * c8 + 1] = *(const float4*)(cj + c8 * 8 + 4);
        }
#pragma unroll
        for (int ii = 0; ii < 2; ++ii) {
            const float* cio = &cish[ii][0];
#pragma unroll
            for (int c8 = 0; c8 < 4; ++c8) {
                float dv[8] = { v[2*c8].x, v[2*c8].y, v[2*c8].z, v[2*c8].w,
                                v[2*c8+1].x, v[2*c8+1].y, v[2*c8+1].z, v[2*c8+1].w };
                float d[8];
#pragma unroll
                for (int e = 0; e < 8; ++e)
                    d[e] = prelu_f(dv[e] - cio[fbq + c8 * 8 + e], a1);
                union { short8 s; unsigned u4[4]; } h8;
#pragma unroll
                for (int p = 0; p < 4; ++p) h8.u4[p] = cvt_pk_bf16(d[2*p], d[2*p+1]);
                *(short8*)(&dth[ii][row][fb + c8 * 8]) = h8.s;
            }
        }
    }
    __syncthreads();

    int lane = tid & 63;
    int wv = tid >> 6;
    int quad = lane >> 4;
    int l15 = lane & 15;
    int kt0 = wv * 2, kt1 = wv * 2 + 1;
    bool has1 = (kt1 < 7);

    const short8* wf = (const short8*)wfrag;
    f32x4 acc[2][2][2];
#pragma unroll
    for (int ii = 0; ii < 2; ++ii)
#pragma unroll
        for (int mt = 0; mt < 2; ++mt)
#pragma unroll
            for (int kk = 0; kk < 2; ++kk) acc[ii][mt][kk] = (f32x4){0.f,0.f,0.f,0.f};

#pragma unroll
    for (int ks = 0; ks < 8; ++ks) {
        short8 b0 = wf[((kt0 * 8 + ks) * 4 + quad) * 16 + l15];
        short8 b1v = has1 ? wf[((kt1 * 8 + ks) * 4 + quad) * 16 + l15] : b0;
#pragma unroll
        for (int ii = 0; ii < 2; ++ii) {
#pragma unroll
            for (int mt = 0; mt < 2; ++mt) {
                short8 a = *(const short8*)(&dth[ii][mt * 16 + l15][ks * 32 + quad * 8]);
                acc[ii][mt][0] = __builtin_amdgcn_mfma_f32_16x16x32_bf16(a, b0, acc[ii][mt][0], 0, 0, 0);
                if (has1)
                    acc[ii][mt][1] = __builtin_amdgcn_mfma_f32_16x16x32_bf16(a, b1v, acc[ii][mt][1], 0, 0, 0);
            }
        }
    }

    int kout0 = kt0 * 16 + l15;
    int kout1 = has1 ? (kt1 * 16 + l15) : 0;
    float bb0 = b1p[kout0], bb1v = b1p[kout1];
    float w20 = w2p[kout0];
    float w21 = has1 ? w2p[kout1] : 0.f;

#pragma unroll
    for (int ii = 0; ii < 2; ++ii) {
        int iv = ii ? i1c : i0;
        float pd0 = pxd[(b * NN + iv) * KP + kout0];
        float pd1 = pxd[(b * NN + iv) * KP + kout1];
#pragma unroll
        for (int mt = 0; mt < 2; ++mt) {
#pragma unroll
            for (int r = 0; r < 4; ++r) {
                int m = mt * 16 + quad * 4 + r;
                int jg = jbase + m;
                int jc = (jg <= SS) ? jg : SS;
                float pe0 = pxe[(b * NN + jc) * KP + kout0];
                float pe1 = pxe[(b * NN + jc) * KP + kout1];
                float h0 = acc[ii][mt][0][r] + pd0 + pe0 + bb0;
                float s = w20 * prelu_f(h0, a2);
                float h1 = acc[ii][mt][1][r] + pd1 + pe1 + bb1v;
                s += w21 * prelu_f(h1, a2);
                s += __shfl_xor(s, 1);
                s += __shfl_xor(s, 2);
                s += __shfl_xor(s, 4);
                s += __shfl_xor(s, 8);
                if (l15 == 0) red[ii][wv][m] = s;
            }
        }
    }
    __syncthreads();
    if (tid < 2 * JT) {
        int ii = tid >> 5;
        int jl = tid & 31;
        int jg = jbase + jl;
        int iv = ii ? i1 : i0;
        if (jg <= SS && (ii == 0 || has_i1)) {
            float tot = red[ii][0][jl] + red[ii][1][jl] + red[ii][2][jl] + red[ii][3][jl] + b2p[0];
            scores[(b * NN + iv) * NN + jg] = tot;
            int d = jg - iv;
            if (d >= 1 && d <= MAXSEG) {
                // rotating-slot layout: slot = iv mod 64 (window<64 => injective)
                dpcol[(b * NN + jg) * 64 + (iv & 63)] = tot;
            }
        }
    }
}

// ---------------- K7: DP v5 — pair-step + 16-deep prefetch -----------------
// dpcol lines were written by scores blocks on OTHER XCDs => L2-miss ~900cy.
// 8-deep prefetch covered only ~600cy of compute per 8 steps (~300cy stall);
// 16-deep fully covers the miss latency.
__global__ void k_dp(const float* __restrict__ dpcol, const int* __restrict__ lengths,
                     float* __restrict__ predF, float* __restrict__ prevF) {
    int b = blockIdx.x;
    int lane = threadIdx.x;          // 64 threads = 1 wave
    int len = lengths[b];
    if (lane == 0) prevF[b * NN] = 0.f;

    float blr = 0.f;                 // lane l holds best[k] for latest k ≡ l (mod 64)
    float predv = 0.f;

#define LO(I) (((I) > MAXSEG) ? ((I) - MAXSEG) : 0)
#define LOADCOL(ii) \
    ( ((ii) <= SS && (((lane - LO(ii)) & 63) < ((ii) - LO(ii)))) \
        ? dpcol[(b * NN + (ii)) * 64 + lane] : 0.f )

    float u0 = LOADCOL(1),  u1 = LOADCOL(2),  u2 = LOADCOL(3),  u3 = LOADCOL(4);
    float u4 = LOADCOL(5),  u5 = LOADCOL(6),  u6 = LOADCOL(7),  u7 = LOADCOL(8);
    float u8 = LOADCOL(9),  u9 = LOADCOL(10), u10 = LOADCOL(11), u11 = LOADCOL(12);
    float u12 = LOADCOL(13), u13 = LOADCOL(14), u14 = LOADCOL(15), u15 = LOADCOL(16);

#define DPP_MAX2(CTRL, va, vb) do {                                           \
        int _ta = __builtin_amdgcn_update_dpp(__float_as_int(va),             \
                      __float_as_int(va), (CTRL), 0xF, 0xF, false);           \
        int _tb = __builtin_amdgcn_update_dpp(__float_as_int(vb),             \
                      __float_as_int(vb), (CTRL), 0xF, 0xF, false);           \
        (va) = fmaxf((va), __int_as_float(_ta));                              \
        (vb) = fmaxf((vb), __int_as_float(_tb));                              \
    } while (0)

#define DP_STEP2(I, BUFA, BUFB) do {                                          \
        int loA_ = LO(I);                                                     \
        int cntA_ = (I) - loA_;                                               \
        int loB_ = LO((I) + 1);                                               \
        int cntBm_ = (I) - loB_;          /* candidates [loB, I-1] */         \
        int offA_ = (lane - loA_) & 63;                                       \
        int offB_ = (lane - loB_) & 63;                                       \
        float vA0_ = (offA_ < cntA_) ? blr + BUFA : -INFINITY;                \
        float vB0_ = (offB_ < cntBm_) ? blr + BUFB : -INFINITY;               \
        float vA_ = vA0_, vB_ = vB0_;                                         \
        DPP_MAX2(0x111, vA_, vB_);   /* row_shr:1  */                         \
        DPP_MAX2(0x112, vA_, vB_);   /* row_shr:2  */                         \
        DPP_MAX2(0x114, vA_, vB_);   /* row_shr:4  */                         \
        DPP_MAX2(0x118, vA_, vB_);   /* row_shr:8  */                         \
        DPP_MAX2(0x142, vA_, vB_);   /* row_bcast:15 */                       \
        DPP_MAX2(0x143, vA_, vB_);   /* row_bcast:31 */                       \
        float mA_ = __int_as_float(                                           \
            __builtin_amdgcn_readlane(__float_as_int(vA_), 63));              \
        float mB_ = __int_as_float(                                           \
            __builtin_amdgcn_readlane(__float_as_int(vB_), 63));              \
        float sI_ = __int_as_float(                                           \
            __builtin_amdgcn_readlane(__float_as_int(BUFB), (I) & 63));       \
        float candI_ = mA_ + sI_;                                             \
        bool takeI_ = candI_ > mB_;                                           \
        float mBf_ = takeI_ ? candI_ : mB_;                                   \
        unsigned long long mkA_ = __ballot(vA0_ == mA_);                      \
        unsigned long long mkB_ = __ballot(vB0_ == mB_);                      \
        int rotA_ = loA_ & 63;                                                \
        int rotB_ = loB_ & 63;                                                \
        unsigned long long mrA_ = rotA_ ? ((mkA_ >> rotA_) | (mkA_ << (64 - rotA_))) : mkA_; \
        unsigned long long mrB_ = rotB_ ? ((mkB_ >> rotB_) | (mkB_ << (64 - rotB_))) : mkB_; \
        int kbA_ = loA_ + (__ffsll(mrA_) - 1);                                \
        int kbB_ = takeI_ ? (I) : (loB_ + (__ffsll(mrB_) - 1));               \
        if (lane == 0) {                                                      \
            prevF[b * NN + (I)] = (float)kbA_;                                \
            prevF[b * NN + (I) + 1] = (float)kbB_;                            \
            if ((I) == len) predv = mA_;                                      \
            if ((I) + 1 == len) predv = mBf_;                                 \
        }                                                                     \
        if (lane == ((I) & 63)) blr = mA_;                                    \
        if (lane == (((I) + 1) & 63)) blr = mBf_;                             \
    } while (0)

    for (int i = 1; i <= SS; i += 16) {
        DP_STEP2(i,      u0,  u1);  u0 = LOADCOL(i + 16);  u1 = LOADCOL(i + 17);
        DP_STEP2(i + 2,  u2,  u3);  u2 = LOADCOL(i + 18);  u3 = LOADCOL(i + 19);
        DP_STEP2(i + 4,  u4,  u5);  u4 = LOADCOL(i + 20);  u5 = LOADCOL(i + 21);
        DP_STEP2(i + 6,  u6,  u7);  u6 = LOADCOL(i + 22);  u7 = LOADCOL(i + 23);
        DP_STEP2(i + 8,  u8,  u9);  u8 = LOADCOL(i + 24);  u9 = LOADCOL(i + 25);
        DP_STEP2(i + 10, u10, u11); u10 = LOADCOL(i + 26); u11 = LOADCOL(i + 27);
        DP_STEP2(i + 12, u12, u13); u12 = LOADCOL(i + 28); u13 = LOADCOL(i + 29);
        DP_STEP2(i + 14, u14, u15); u14 = LOADCOL(i + 30); u15 = LOADCOL(i + 31);
    }
#undef DP_STEP2
#undef DPP_MAX2
#undef LOADCOL
#undef LO
    if (lane == 0) predF[b] = predv;
}

// ---------------- launch ---------------------------------------------------
extern "C" void kernel_launch(void* const* d_in, const int* in_sizes, int n_in,
                              void* d_out, int out_size, void* d_ws, size_t ws_size,
                              hipStream_t stream) {
    const float* x    = (const float*)d_in[0];
    const int* lengths= (const int*)d_in[1];
    const float* Wi_f = (const float*)d_in[2];
    const float* Wh_f = (const float*)d_in[3];
    const float* b_f  = (const float*)d_in[4];
    const float* Wi_b = (const float*)d_in[5];
    const float* Wh_b = (const float*)d_in[6];
    const float* b_b  = (const float*)d_in[7];
    const float* a1   = (const float*)d_in[8];
    const float* W1   = (const float*)d_in[9];
    const float* b1   = (const float*)d_in[10];
    const float* a2   = (const float*)d_in[11];
    const float* W2   = (const float*)d_in[12];
    const float* b2   = (const float*)d_in[13];
    const float* ac1  = (const float*)d_in[14];
    const float* Wc1  = (const float*)d_in[15];
    const float* bc1  = (const float*)d_in[16];
    const float* ac2  = (const float*)d_in[17];
    const float* Wc2  = (const float*)d_in[18];
    const float* bc2  = (const float*)d_in[19];
    const float* ab1  = (const float*)d_in[20];
    const float* Wb1  = (const float*)d_in[21];
    const float* bb1  = (const float*)d_in[22];
    const float* ab2  = (const float*)d_in[23];
    const float* Wb2  = (const float*)d_in[24];
    const float* bb2  = (const float*)d_in[25];

    float* out = (float*)d_out;
    float* scores = out + SCORES_OFF;
    float* cls    = out + CLS_OFF;
    float* bin    = out + BIN_OFF;
    float* pred   = out + PRED_OFF;
    float* prev   = out + PREV_OFF;

    float* ws    = (float*)d_ws;
    float* gx    = ws + WS_GX;
    float* dpcol = ws + WS_GX;       // reuse: gx dead after k_lstm_rec
    float* rnn   = ws + WS_RNN;
    float* cum   = ws + WS_CUM;
    float* pxd   = ws + WS_PXD;
    float* pxe   = ws + WS_PXE;
    float* w2p   = ws + WS_W2P;
    float* b1p   = ws + WS_B1P;
    __half* whp  = (__half*)(ws + WS_WHP);
    short* wfC   = (short*)(ws + WS_WFRAGC);
    short* wfD   = (short*)(ws + WS_WFRAGD);
    short* wfE   = (short*)(ws + WS_WFRAGE);
    short* wfHC  = (short*)(ws + WS_WFRAGHC);
    short* wfHB  = (short*)(ws + WS_WFRAGHB);
    float* bc1p  = ws + WS_BC1P;
    float* bb1p  = ws + WS_BB1P;

    k_lstm_pre<<<PREPBLKS, 256, 0, stream>>>(x, Wi_f, b_f, Wi_b, b_b, gx,
                                             Wh_f, Wh_b, whp);
    k_lstm_rec<<<4 + WPACKS, 256, 0, stream>>>((const _Float16*)whp, gx, rnn,
                                               W1, W2, b1, Wc1, Wb1, bc1, bb1,
                                               wfC, wfD, wfE, wfHC, wfHB,
                                               w2p, b1p, bc1p, bb1p);
    k_cum_mlp<<<BB + PXBLKS + HDBLKS, 256, 0, stream>>>(rnn, cum, a1, ac1, ab1,
                                                        wfD, wfE, wfHC, wfHB,
                                                        bc1p, bb1p, ac2, ab2,
                                                        Wc2, bc2, Wb2, bb2,
                                                        pxd, pxe, cls, bin);
    k_scores<<<BB * NP2 * JTILES, 256, 0, stream>>>(cum, wfC, pxd, pxe, b1p, w2p, b2,
                                                    a1, a2, scores, dpcol);
    k_dp<<<BB, 64, 0, stream>>>(dpcol, lengths, pred, prev);
}